// Round 14
// baseline (227.250 us; speedup 1.0000x reference)
//
#include <hip/hip_runtime.h>

typedef __bf16 bf16_t;
typedef bf16_t bf16x8 __attribute__((ext_vector_type(8)));
typedef bf16_t bf16x4 __attribute__((ext_vector_type(4)));
typedef bf16_t bf16x2 __attribute__((ext_vector_type(2)));
typedef float f32x4 __attribute__((ext_vector_type(4)));
typedef unsigned long long u64;

#define N_PTS 8192
#define C_DIM 256
#define K_NN 16

// ---- spatial grid for exact KNN ----
#define GRID_G    16
#define GRID_NC   (GRID_G * GRID_G * GRID_G)   // 4096 cells
#define GRID_CELL 6.25f                        // 100 / 16
#define GRID_INV  0.16f                        // 16 / 100

// ---------------------------------------------------------------- prep (all-parallel, no long-pole block):
#define CAST_NBLK 2048
#define PREPW_NBLK 320
__global__ __launch_bounds__(256) void prep_kernel(
    const float* __restrict__ feats, bf16_t* __restrict__ fb,
    const float* __restrict__ w0, const float* __restrict__ w1,
    const float* __restrict__ w2, const float* __restrict__ w3,
    const float* __restrict__ w4, bf16_t* __restrict__ wt_base,
    int* __restrict__ cellCount, int* __restrict__ gcount) {
    const int b = blockIdx.x;
    const int t = threadIdx.x;

    if (b < CAST_NBLK) {
        int i = (b * 256 + t) * 4;
        float4 v = *(const float4*)(feats + i);
        bf16x4 o;
        o[0] = (bf16_t)v.x; o[1] = (bf16_t)v.y; o[2] = (bf16_t)v.z; o[3] = (bf16_t)v.w;
        *(bf16x4*)(fb + i) = o;
    } else if (b < CAST_NBLK + PREPW_NBLK) {
        int pb = b - CAST_NBLK;
        int m = pb >> 6;
        int bx = pb & 63;
        const float* src = (m == 0) ? w0 : (m == 1) ? w1 : (m == 2) ? w2 : (m == 3) ? w3 : w4;
        bf16_t* dst = wt_base + m * (C_DIM * C_DIM);
#pragma unroll
        for (int i = 0; i < 4; ++i) {
            int o = bx * 1024 + i * 256 + t;
            int tkb = o >> 9;
            int rem = o & 511;
            int lm = rem >> 5;
            int r = rem & 31;
            int k = (tkb & 7) * 32 + r;
            int n = (tkb >> 3) * 16 + lm;
            dst[o] = (bf16_t)src[k * C_DIM + n];
        }
    } else {
        int zb = b - CAST_NBLK - PREPW_NBLK;
        cellCount[zb * 256 + t] = 0;
        if (zb == 0 && t == 0) *gcount = 0;
    }
}

// ---------------------------------------------------------------- grid build: count per cell
__global__ __launch_bounds__(256) void grid_count_kernel(const float* __restrict__ coords,
                                                         int* __restrict__ cellCount,
                                                         int* __restrict__ cid) {
    int i = blockIdx.x * 256 + threadIdx.x;
    float x = coords[3 * i + 0], y = coords[3 * i + 1], z = coords[3 * i + 2];
    int cx = (int)(x * GRID_INV); if (cx > GRID_G - 1) cx = GRID_G - 1;
    int cy = (int)(y * GRID_INV); if (cy > GRID_G - 1) cy = GRID_G - 1;
    int cz = (int)(z * GRID_INV); if (cz > GRID_G - 1) cz = GRID_G - 1;
    int c = (cx * GRID_G + cy) * GRID_G + cz;
    cid[i] = c;
    atomicAdd(&cellCount[c], 1);
}

// ---------------------------------------------------------------- grid build: exclusive scan (1 block)
__global__ __launch_bounds__(256) void grid_scan_kernel(const int* __restrict__ cellCount,
                                                        int* __restrict__ cellStart,
                                                        int* __restrict__ cellPtr) {
    __shared__ int part[256];
    int t = threadIdx.x;
    int base = t * 16;
    int v[16];
    int sum = 0;
#pragma unroll
    for (int i = 0; i < 16; ++i) { v[i] = cellCount[base + i]; sum += v[i]; }
    part[t] = sum;
    __syncthreads();
    for (int off = 1; off < 256; off <<= 1) {
        int x = (t >= off) ? part[t - off] : 0;
        __syncthreads();
        part[t] += x;
        __syncthreads();
    }
    int acc = part[t] - sum;
#pragma unroll
    for (int i = 0; i < 16; ++i) {
        cellStart[base + i] = acc;
        cellPtr[base + i] = acc;
        acc += v[i];
    }
    if (t == 255) cellStart[GRID_NC] = acc;
}

// ---------------------------------------------------------------- grid build: scatter into sorted float4 plane
__global__ __launch_bounds__(256) void grid_scatter_kernel(
    const float* __restrict__ coords, const int* __restrict__ cid, int* __restrict__ cellPtr,
    float4* __restrict__ sp4, int* __restrict__ sidx) {
    int i = blockIdx.x * 256 + threadIdx.x;
    int c = cid[i];
    int pos = atomicAdd(&cellPtr[c], 1);
    float x = coords[3 * i + 0], y = coords[3 * i + 1], z = coords[3 * i + 2];
    // exact same bit sequence as reference sq:
    float sq = __fadd_rn(__fadd_rn(__fmul_rn(x, x), __fmul_rn(y, y)), __fmul_rn(z, z));
    sp4[pos] = make_float4(x, y, z, sq);
    sidx[pos] = i;
}

// ---------------------------------------------------------------- KNN via grid window (1 wave per query)
__global__ __launch_bounds__(256) void knn_grid_kernel(
    const float* __restrict__ coords, const int* __restrict__ cellStart,
    const float4* __restrict__ sp4, const int* __restrict__ sidx,
    int* __restrict__ idx_out, int* __restrict__ glist, int* __restrict__ gcount) {
    const int tid = threadIdx.x;
    const int wave = tid >> 6, lane = tid & 63;
    const int q = blockIdx.x * 4 + wave;

    __shared__ int segBase[4][25];
    __shared__ int segPref[4][26];

    const float qx = coords[3 * q + 0], qy = coords[3 * q + 1], qz = coords[3 * q + 2];
    const float sqi = __fadd_rn(__fadd_rn(__fmul_rn(qx, qx), __fmul_rn(qy, qy)),
                                __fmul_rn(qz, qz));

    int cx = (int)(qx * GRID_INV); if (cx > GRID_G - 1) cx = GRID_G - 1;
    int cy = (int)(qy * GRID_INV); if (cy > GRID_G - 1) cy = GRID_G - 1;
    int cz = (int)(qz * GRID_INV); if (cz > GRID_G - 1) cz = GRID_G - 1;
    int wx0 = cx - 2; if (wx0 < 0) wx0 = 0;
    int wx1 = cx + 2; if (wx1 > GRID_G - 1) wx1 = GRID_G - 1;
    int wy0 = cy - 2; if (wy0 < 0) wy0 = 0;
    int wy1 = cy + 2; if (wy1 > GRID_G - 1) wy1 = GRID_G - 1;
    int wz0 = cz - 2; if (wz0 < 0) wz0 = 0;
    int wz1 = cz + 2; if (wz1 > GRID_G - 1) wz1 = GRID_G - 1;

    const float INF = __int_as_float(0x7f800000);
    float rc = INF;
    if (wx0 > 0)          rc = fminf(rc, qx - (float)wx0 * GRID_CELL);
    if (wx1 < GRID_G - 1) rc = fminf(rc, (float)(wx1 + 1) * GRID_CELL - qx);
    if (wy0 > 0)          rc = fminf(rc, qy - (float)wy0 * GRID_CELL);
    if (wy1 < GRID_G - 1) rc = fminf(rc, (float)(wy1 + 1) * GRID_CELL - qy);
    if (wz0 > 0)          rc = fminf(rc, qz - (float)wz0 * GRID_CELL);
    if (wz1 < GRID_G - 1) rc = fminf(rc, (float)(wz1 + 1) * GRID_CELL - qz);
    float rc2 = rc * rc * 0.9999f;

    int nx = wx1 - wx0 + 1, nyc = wy1 - wy0 + 1;
    int ns = nx * nyc;
    if (lane < ns) {
        int scx = wx0 + lane / nyc;
        int scy = wy0 + lane % nyc;
        int b = (scx * GRID_G + scy) * GRID_G;
        int s0 = cellStart[b + wz0];
        int s1 = cellStart[b + wz1 + 1];
        segBase[wave][lane] = s0;
        segPref[wave][lane] = s1 - s0;
    }
    __syncthreads();
    if (lane == 0) {
        int acc = 0;
        for (int s = 0; s < ns; ++s) { int l = segPref[wave][s]; segPref[wave][s] = acc; acc += l; }
        segPref[wave][ns] = acc;
    }
    __syncthreads();

    const int M = segPref[wave][ns];
    bool flag = (M < K_NN) || (M > 320);

    // ---- load up to 5 keys per lane directly from the window (static slot indexing)
    u64 k0 = ~0ull, k1 = ~0ull, k2 = ~0ull, k3 = ~0ull, k4 = ~0ull;
    {
        int s = 0;
#pragma unroll
        for (int slot = 0; slot < 5; ++slot) {
            int t = lane + slot * 64;
            if (t < M) {
                while (t >= segPref[wave][s + 1]) ++s;
                int pos = segBase[wave][s] + (t - segPref[wave][s]);
                float4 v = sp4[pos];
                float dot = __fmaf_rn(v.z, qz, __fmaf_rn(v.y, qy, __fmul_rn(v.x, qx)));
                float d2 = __fsub_rn(__fadd_rn(sqi, v.w), __fmul_rn(2.0f, dot));
                unsigned u = __float_as_uint(d2);
                u = (u & 0x80000000u) ? ~u : (u | 0x80000000u);
                u64 key = (((u64)u) << 32) | (unsigned)sidx[pos];
                if (slot == 0) k0 = key;
                else if (slot == 1) k1 = key;
                else if (slot == 2) k2 = key;
                else if (slot == 3) k3 = key;
                else k4 = key;
            }
        }
    }

    // ---- selection: 16 wave-argmin rounds over unique (d2, idx) keys
    u64 lm2 = k0; int li = 0;
    if (k1 < lm2) { lm2 = k1; li = 1; }
    if (k2 < lm2) { lm2 = k2; li = 2; }
    if (k3 < lm2) { lm2 = k3; li = 3; }
    if (k4 < lm2) { lm2 = k4; li = 4; }
    int keep = 0;
    u64 last = ~0ull;
#pragma unroll 1
    for (int r = 0; r < 16; ++r) {
        u64 w = lm2;
#pragma unroll
        for (int off = 1; off < 64; off <<= 1) {
            u64 o = __shfl_xor(w, off);
            w = (o < w) ? o : w;
        }
        if (lane == r) keep = (int)(unsigned)(w & 0xffffffffull);
        last = w;
        if (lm2 == w) {  // unique winner: retire slot, recompute local min
            if (li == 0) k0 = ~0ull;
            else if (li == 1) k1 = ~0ull;
            else if (li == 2) k2 = ~0ull;
            else if (li == 3) k3 = ~0ull;
            else k4 = ~0ull;
            lm2 = k0; li = 0;
            if (k1 < lm2) { lm2 = k1; li = 1; }
            if (k2 < lm2) { lm2 = k2; li = 2; }
            if (k3 < lm2) { lm2 = k3; li = 3; }
            if (k4 < lm2) { lm2 = k4; li = 4; }
        }
    }

    // ---- coverage check on exact d16
    if (!flag) {
        unsigned ou = (unsigned)(last >> 32);
        unsigned db = (ou & 0x80000000u) ? (ou ^ 0x80000000u) : ~ou;
        float d16 = __uint_as_float(db);
        if (d16 >= rc2) flag = true;
    }
    if (flag && lane == 0) {
        int sl = atomicAdd(gcount, 1);
        glist[sl] = q;
    }
    if (lane < 16) idx_out[q * K_NN + lane] = keep;   // flagged queries overwritten by fallback
}

// ---------------------------------------------------------------- KNN brute-force fallback for flagged queries
// Grid-stride over glist (32 blocks; ~40 flagged queries expected).
__global__ __launch_bounds__(256) void knn_fallback_kernel(const float* __restrict__ coords,
                                                           const int* __restrict__ glist,
                                                           const int* __restrict__ gcount,
                                                           int* __restrict__ idx_out) {
    const int count = *gcount;
    const int tid = threadIdx.x;
    const int wave = tid >> 6, lane = tid & 63;
    __shared__ float red16[4][16];
    __shared__ u64 cand[4][256];
    __shared__ int cnt[4];
    __shared__ int qids[4];
    const float INF = __int_as_float(0x7f800000);
    const float* cp = coords + tid * 96;

#pragma unroll 1
    for (int n0 = blockIdx.x * 4; n0 < count; n0 += gridDim.x * 4) {
        if (tid < 4) {
            cnt[tid] = 0;
            int slot = n0 + tid;
            qids[tid] = glist[slot < count ? slot : count - 1];
        }
        __syncthreads();

        float qx[4], qy[4], qz[4], sqi[4];
#pragma unroll
        for (int q = 0; q < 4; ++q) {
            int id = qids[q];
            qx[q] = coords[3 * id + 0];
            qy[q] = coords[3 * id + 1];
            qz[q] = coords[3 * id + 2];
            sqi[q] = __fadd_rn(__fadd_rn(__fmul_rn(qx[q], qx[q]), __fmul_rn(qy[q], qy[q])),
                               __fmul_rn(qz[q], qz[q]));
        }

        float lmin[4] = {INF, INF, INF, INF};
#pragma unroll
        for (int c = 0; c < 4; ++c) {
            float buf[24];
#pragma unroll
            for (int v = 0; v < 6; ++v)
                *(float4*)(buf + v * 4) = *(const float4*)(cp + c * 24 + v * 4);
#pragma unroll
            for (int p = 0; p < 8; ++p) {
                float x = buf[3 * p + 0], y = buf[3 * p + 1], z = buf[3 * p + 2];
                float sqj = __fadd_rn(__fadd_rn(__fmul_rn(x, x), __fmul_rn(y, y)),
                                      __fmul_rn(z, z));
#pragma unroll
                for (int q = 0; q < 4; ++q) {
                    float dot = __fmaf_rn(z, qz[q], __fmaf_rn(y, qy[q], __fmul_rn(x, qx[q])));
                    float d2 = __fsub_rn(__fadd_rn(sqi[q], sqj), __fmul_rn(2.0f, dot));
                    lmin[q] = fminf(lmin[q], d2);
                }
            }
        }

#pragma unroll
        for (int q = 0; q < 4; ++q) {
            float g = lmin[q];
            g = fminf(g, __shfl_xor(g, 1));
            g = fminf(g, __shfl_xor(g, 2));
            g = fminf(g, __shfl_xor(g, 4));
            g = fminf(g, __shfl_xor(g, 8));
            if ((lane & 15) == 0) red16[q][wave * 4 + (lane >> 4)] = g;
        }
        __syncthreads();

        float tau[4];
#pragma unroll
        for (int q = 0; q < 4; ++q) {
            float t = red16[q][0];
#pragma unroll
            for (int i = 1; i < 16; ++i) t = fmaxf(t, red16[q][i]);
            tau[q] = t;
        }

#pragma unroll
        for (int c = 0; c < 4; ++c) {
            float buf[24];
#pragma unroll
            for (int v = 0; v < 6; ++v)
                *(float4*)(buf + v * 4) = *(const float4*)(cp + c * 24 + v * 4);
#pragma unroll
            for (int p = 0; p < 8; ++p) {
                float x = buf[3 * p + 0], y = buf[3 * p + 1], z = buf[3 * p + 2];
                float sqj = __fadd_rn(__fadd_rn(__fmul_rn(x, x), __fmul_rn(y, y)),
                                      __fmul_rn(z, z));
                int j = tid * 32 + c * 8 + p;
#pragma unroll
                for (int q = 0; q < 4; ++q) {
                    float dot = __fmaf_rn(z, qz[q], __fmaf_rn(y, qy[q], __fmul_rn(x, qx[q])));
                    float d2 = __fsub_rn(__fadd_rn(sqi[q], sqj), __fmul_rn(2.0f, dot));
                    if (d2 <= tau[q]) {
                        unsigned u = __float_as_uint(d2);
                        u = (u & 0x80000000u) ? ~u : (u | 0x80000000u);
                        int slot = atomicAdd(&cnt[q], 1);
                        if (slot < 256)
                            cand[q][slot] = (((u64)u) << 32) | (unsigned)j;
                    }
                }
            }
        }
        __syncthreads();

        int m = cnt[wave]; if (m > 256) m = 256;
        u64 k0 = ~0ull, k1 = ~0ull, k2 = ~0ull, k3 = ~0ull;
        if (lane < m) k0 = cand[wave][lane];
        if (lane + 64 < m) k1 = cand[wave][lane + 64];
        if (lane + 128 < m) k2 = cand[wave][lane + 128];
        if (lane + 192 < m) k3 = cand[wave][lane + 192];
        u64 lm2 = k0; int li = 0;
        if (k1 < lm2) { lm2 = k1; li = 1; }
        if (k2 < lm2) { lm2 = k2; li = 2; }
        if (k3 < lm2) { lm2 = k3; li = 3; }
        int keep = 0;
#pragma unroll 1
        for (int r = 0; r < 16; ++r) {
            u64 w = lm2;
#pragma unroll
            for (int off = 1; off < 64; off <<= 1) {
                u64 o = __shfl_xor(w, off);
                w = (o < w) ? o : w;
            }
            if (lane == r) keep = (int)(unsigned)(w & 0xffffffffull);
            if (lm2 == w) {
                if (li == 0) k0 = ~0ull;
                else if (li == 1) k1 = ~0ull;
                else if (li == 2) k2 = ~0ull;
                else k3 = ~0ull;
                lm2 = k0; li = 0;
                if (k1 < lm2) { lm2 = k1; li = 1; }
                if (k2 < lm2) { lm2 = k2; li = 2; }
                if (k3 < lm2) { lm2 = k3; li = 3; }
            }
        }
        if (n0 + wave < count && lane < 16)
            idx_out[qids[wave] * K_NN + lane] = keep;
        __syncthreads();   // cand/cnt reuse safe before next grid-stride iteration
    }
}

// ---------------------------------------------------------------- proj: T/PG = feats@{theta,phi,g}+b
__global__ __launch_bounds__(256, 2) void proj_kernel(
    const bf16_t* __restrict__ fb, const bf16_t* __restrict__ wt_base,
    const float* __restrict__ tb, const float* __restrict__ pb, const float* __restrict__ gb,
    float* __restrict__ T, bf16_t* __restrict__ PG) {
    const int sel = blockIdx.y;
    const int half = blockIdx.z;
    const bf16_t* Wt = wt_base + sel * (C_DIM * C_DIM);
    const float* bias = (sel == 0) ? tb : (sel == 1) ? pb : gb;
    const int wave = threadIdx.x >> 6, lane = threadIdx.x & 63;
    const int q = lane >> 4, lm = lane & 15;
    const int m0 = blockIdx.x * 64;

    bf16x8 bfr[2][8];
#pragma unroll
    for (int ti = 0; ti < 2; ++ti)
#pragma unroll
        for (int kb = 0; kb < 8; ++kb)
            bfr[ti][kb] = *(const bf16x8*)(Wt + (((half * 8 + wave * 2 + ti) * 8 + kb) << 9) + lm * 32 + q * 8);

    float bv[2];
#pragma unroll
    for (int ti = 0; ti < 2; ++ti) bv[ti] = bias[(half * 8 + wave * 2 + ti) * 16 + lm];

#pragma unroll
    for (int p = 0; p < 4; ++p) {
        const bf16_t* arow = fb + (m0 + p * 16 + lm) * C_DIM + q * 8;
        f32x4 acc[2];
        acc[0] = (f32x4){0.f, 0.f, 0.f, 0.f};
        acc[1] = (f32x4){0.f, 0.f, 0.f, 0.f};
#pragma unroll
        for (int kb = 0; kb < 8; ++kb) {
            bf16x8 a = *(const bf16x8*)(arow + kb * 32);
            acc[0] = __builtin_amdgcn_mfma_f32_16x16x32_bf16(a, bfr[0][kb], acc[0], 0, 0, 0);
            acc[1] = __builtin_amdgcn_mfma_f32_16x16x32_bf16(a, bfr[1][kb], acc[1], 0, 0, 0);
        }

#pragma unroll
        for (int ti = 0; ti < 2; ++ti) {
            int c = (half * 8 + wave * 2 + ti) * 16 + lm;
#pragma unroll
            for (int r = 0; r < 4; ++r) {
                float v = acc[ti][r] + bv[ti];
                int off = (m0 + p * 16 + q * 4 + r) * C_DIM + c;
                if (sel == 0) T[off] = v;
                else if (sel == 1) PG[2 * off] = (bf16_t)v;
                else PG[2 * off + 1] = (bf16_t)v;
            }
        }
    }
}

// ---------------------------------------------------------------- pe1 + pe2 GEMM + softmax + weighted G-sum
//                                                                  + fused FINAL GEMM (out = y@W_w + W_b + feats)
// 512-thread / 8-wave, __launch_bounds__(512,4) (proven; reg need >85, no cap <128).
// 2-LP PHASES: the compiler drains vmcnt(0) at every __syncthreads (round-13
// lesson: per-lp barriers killed the gather prefetch). Staging h for TWO lp per
// barrier (hbuf[2][2][...], 33.8KB) halves the barrier count to 8 and gives each
// drain 2-3x the compute cover (softmax(lp0)+MFMA(lp1)+softmax(lp1)). Next-phase
// gathers batch-issued right after the phase's first MFMA into named register
// sets A0/A1 <- B0/B1 (static indexing only).
#define HPAD 264
#define P_BLK 16
#define NPH (P_BLK / 2)
#define HROWS (P_BLK * 16)
__global__ __launch_bounds__(512, 4) void pe2_fused_kernel(
    const float* __restrict__ coords, const int* __restrict__ idx,
    const float* __restrict__ T, const bf16_t* __restrict__ PG,
    const float* __restrict__ w1, const float* __restrict__ b1, const float* __restrict__ b2,
    const bf16_t* __restrict__ Wt2, const bf16_t* __restrict__ Wt3,
    const float* __restrict__ Wb, const float* __restrict__ feats,
    float* __restrict__ out) {
    __shared__ __align__(16) bf16_t hbuf[2][2][16 * HPAD];
    __shared__ __align__(16) bf16_t yl[16][HPAD];
    __shared__ float dxyz[HROWS][3];
    __shared__ int idxl[HROWS];
    const int tid = threadIdx.x;
    const int p0 = blockIdx.x * P_BLK;
    const int wave = tid >> 6, lane = tid & 63;
    const int q = lane >> 4, lm = lane & 15;

    // 2 col-tiles per wave; global tile index t = wave*2 + ti (0..15)
    bf16x8 bfr[2][8];
#pragma unroll
    for (int ti = 0; ti < 2; ++ti)
#pragma unroll
        for (int kb = 0; kb < 8; ++kb)
            bfr[ti][kb] = *(const bf16x8*)(Wt2 + (((wave * 2 + ti) * 8 + kb) << 9) + lm * 32 + q * 8);
    float b2c[2];
#pragma unroll
    for (int ti = 0; ti < 2; ++ti) b2c[ti] = b2[(wave * 2 + ti) * 16 + lm];

    if (tid < HROWS) {
        int n = p0 + (tid >> 4);
        int j = idx[n * K_NN + (tid & 15)];
        idxl[tid] = j;
        dxyz[tid][0] = coords[3 * j + 0] - coords[3 * n + 0];
        dxyz[tid][1] = coords[3 * j + 1] - coords[3 * n + 1];
        dxyz[tid][2] = coords[3 * j + 2] - coords[3 * n + 2];
    }
    __syncthreads();

    // pe1: thread handles column hc, rows rh..rh+7 of each 16-row tile
    const int hc = tid & 255;
    const int rh = (tid >> 8) * 8;
    const float wx = w1[hc], wy = w1[C_DIM + hc], wz = w1[2 * C_DIM + hc], bb = b1[hc];

    // prologue: stage h tiles for phase 0 (lp 0 and 1)
#pragma unroll
    for (int r = 0; r < 8; ++r) {
        int row = rh + r;
        float pre0 = dxyz[row][0] * wx + dxyz[row][1] * wy + dxyz[row][2] * wz + bb;
        hbuf[0][0][row * HPAD + hc] = (bf16_t)fmaxf(pre0, 0.0f);
        float pre1 = dxyz[16 + row][0] * wx + dxyz[16 + row][1] * wy + dxyz[16 + row][2] * wz + bb;
        hbuf[0][1][row * HPAD + hc] = (bf16_t)fmaxf(pre1, 0.0f);
    }

    // prologue: issue gathers for phase 0 (lp 0 -> A0, lp 1 -> A1)
    bf16x2 pgA0[2][4], pgA1[2][4];
    float TnA0[2], TnA1[2];
    {
        int jr0[4], jr1[4];
#pragma unroll
        for (int r = 0; r < 4; ++r) {
            jr0[r] = idxl[q * 4 + r];
            jr1[r] = idxl[16 + q * 4 + r];
        }
#pragma unroll
        for (int ti = 0; ti < 2; ++ti) {
            int c = (wave * 2 + ti) * 16 + lm;
            TnA0[ti] = T[p0 * C_DIM + c];
            TnA1[ti] = T[(p0 + 1) * C_DIM + c];
#pragma unroll
            for (int r = 0; r < 4; ++r) {
                pgA0[ti][r] = *(const bf16x2*)(PG + 2 * (jr0[r] * C_DIM + c));
                pgA1[ti][r] = *(const bf16x2*)(PG + 2 * (jr1[r] * C_DIM + c));
            }
        }
    }
    __syncthreads();

#pragma unroll 1
    for (int ph = 0; ph < NPH; ++ph) {
        const int lp0 = ph * 2;
        const int cur = ph & 1;

        // ---- stage h tiles for phase ph+1
        if (ph + 1 < NPH) {
            int rb = (ph + 1) * 32;
#pragma unroll
            for (int r = 0; r < 8; ++r) {
                int row = rh + r;
                float pre0 = dxyz[rb + row][0] * wx + dxyz[rb + row][1] * wy
                           + dxyz[rb + row][2] * wz + bb;
                hbuf[cur ^ 1][0][row * HPAD + hc] = (bf16_t)fmaxf(pre0, 0.0f);
                float pre1 = dxyz[rb + 16 + row][0] * wx + dxyz[rb + 16 + row][1] * wy
                           + dxyz[rb + 16 + row][2] * wz + bb;
                hbuf[cur ^ 1][1][row * HPAD + hc] = (bf16_t)fmaxf(pre1, 0.0f);
            }
        }

        // ---- MFMA for lp0
        const bf16_t* hrow0 = &hbuf[cur][0][lm * HPAD + q * 8];
        f32x4 acc0[2];
        acc0[0] = (f32x4){0.f, 0.f, 0.f, 0.f};
        acc0[1] = (f32x4){0.f, 0.f, 0.f, 0.f};
#pragma unroll
        for (int kb = 0; kb < 8; ++kb) {
            bf16x8 a = *(const bf16x8*)(hrow0 + kb * 32);
            acc0[0] = __builtin_amdgcn_mfma_f32_16x16x32_bf16(a, bfr[0][kb], acc0[0], 0, 0, 0);
            acc0[1] = __builtin_amdgcn_mfma_f32_16x16x32_bf16(a, bfr[1][kb], acc0[1], 0, 0, 0);
        }

        // ---- batch-issue gathers for phase ph+1 (drained at this phase's barrier;
        //      cover = softmax(lp0) + MFMA(lp1) + softmax(lp1))
        bf16x2 pgB0[2][4], pgB1[2][4];
        float TnB0[2], TnB1[2];
        if (ph + 1 < NPH) {
            int np0 = p0 + lp0 + 2;
            int jr0[4], jr1[4];
#pragma unroll
            for (int r = 0; r < 4; ++r) {
                jr0[r] = idxl[(lp0 + 2) * 16 + q * 4 + r];
                jr1[r] = idxl[(lp0 + 3) * 16 + q * 4 + r];
            }
#pragma unroll
            for (int ti = 0; ti < 2; ++ti) {
                int c = (wave * 2 + ti) * 16 + lm;
                TnB0[ti] = T[np0 * C_DIM + c];
                TnB1[ti] = T[(np0 + 1) * C_DIM + c];
#pragma unroll
                for (int r = 0; r < 4; ++r) {
                    pgB0[ti][r] = *(const bf16x2*)(PG + 2 * (jr0[r] * C_DIM + c));
                    pgB1[ti][r] = *(const bf16x2*)(PG + 2 * (jr1[r] * C_DIM + c));
                }
            }
        }

        // ---- softmax + weighted G-sum for lp0 (uses A0)
#pragma unroll
        for (int ti = 0; ti < 2; ++ti) {
            int c = (wave * 2 + ti) * 16 + lm;
            float df[4];
#pragma unroll
            for (int r = 0; r < 4; ++r) {
                float pe = acc0[ti][r] + b2c[ti];
                df[r] = (pe * (TnA0[ti] - (float)pgA0[ti][r][0]) + pe) * 0.0625f;
            }
            float mx = fmaxf(fmaxf(df[0], df[1]), fmaxf(df[2], df[3]));
            mx = fmaxf(mx, __shfl_xor(mx, 16));
            mx = fmaxf(mx, __shfl_xor(mx, 32));
            float e[4], s = 0.f;
#pragma unroll
            for (int r = 0; r < 4; ++r) { e[r] = __expf(df[r] - mx); s += e[r]; }
            s += __shfl_xor(s, 16);
            s += __shfl_xor(s, 32);
            float inv = 1.0f / s;
            float y = 0.f;
#pragma unroll
            for (int r = 0; r < 4; ++r) y += e[r] * inv * (float)pgA0[ti][r][1];
            y += __shfl_xor(y, 16);
            y += __shfl_xor(y, 32);
            if (q == 0) yl[lp0][c] = (bf16_t)y;
        }

        // ---- MFMA for lp1
        const bf16_t* hrow1 = &hbuf[cur][1][lm * HPAD + q * 8];
        f32x4 acc1[2];
        acc1[0] = (f32x4){0.f, 0.f, 0.f, 0.f};
        acc1[1] = (f32x4){0.f, 0.f, 0.f, 0.f};
#pragma unroll
        for (int kb = 0; kb < 8; ++kb) {
            bf16x8 a = *(const bf16x8*)(hrow1 + kb * 32);
            acc1[0] = __builtin_amdgcn_mfma_f32_16x16x32_bf16(a, bfr[0][kb], acc1[0], 0, 0, 0);
            acc1[1] = __builtin_amdgcn_mfma_f32_16x16x32_bf16(a, bfr[1][kb], acc1[1], 0, 0, 0);
        }

        // ---- softmax + weighted G-sum for lp1 (uses A1)
#pragma unroll
        for (int ti = 0; ti < 2; ++ti) {
            int c = (wave * 2 + ti) * 16 + lm;
            float df[4];
#pragma unroll
            for (int r = 0; r < 4; ++r) {
                float pe = acc1[ti][r] + b2c[ti];
                df[r] = (pe * (TnA1[ti] - (float)pgA1[ti][r][0]) + pe) * 0.0625f;
            }
            float mx = fmaxf(fmaxf(df[0], df[1]), fmaxf(df[2], df[3]));
            mx = fmaxf(mx, __shfl_xor(mx, 16));
            mx = fmaxf(mx, __shfl_xor(mx, 32));
            float e[4], s = 0.f;
#pragma unroll
            for (int r = 0; r < 4; ++r) { e[r] = __expf(df[r] - mx); s += e[r]; }
            s += __shfl_xor(s, 16);
            s += __shfl_xor(s, 32);
            float inv = 1.0f / s;
            float y = 0.f;
#pragma unroll
            for (int r = 0; r < 4; ++r) y += e[r] * inv * (float)pgA1[ti][r][1];
            y += __shfl_xor(y, 16);
            y += __shfl_xor(y, 32);
            if (q == 0) yl[lp0 + 1][c] = (bf16_t)y;
        }

        // ---- rotate prefetch sets A <- B
#pragma unroll
        for (int ti = 0; ti < 2; ++ti) {
            TnA0[ti] = TnB0[ti];
            TnA1[ti] = TnB1[ti];
#pragma unroll
            for (int r = 0; r < 4; ++r) {
                pgA0[ti][r] = pgB0[ti][r];
                pgA1[ti][r] = pgB1[ti][r];
            }
        }
        __syncthreads();   // hbuf[cur^1] + yl writes visible; drains next-phase gathers
    }

    // ---- fused final GEMM: out[p0..p0+15] = y @ W_w + W_b + feats
#pragma unroll
    for (int ti = 0; ti < 2; ++ti)
#pragma unroll
        for (int kb = 0; kb < 8; ++kb)
            bfr[ti][kb] = *(const bf16x8*)(Wt3 + (((wave * 2 + ti) * 8 + kb) << 9) + lm * 32 + q * 8);
    float bw[2];
#pragma unroll
    for (int ti = 0; ti < 2; ++ti) bw[ti] = Wb[(wave * 2 + ti) * 16 + lm];

    f32x4 acc2[2];
    acc2[0] = (f32x4){0.f, 0.f, 0.f, 0.f};
    acc2[1] = (f32x4){0.f, 0.f, 0.f, 0.f};
#pragma unroll
    for (int kb = 0; kb < 8; ++kb) {
        bf16x8 a = *(const bf16x8*)(&yl[lm][kb * 32 + q * 8]);
        acc2[0] = __builtin_amdgcn_mfma_f32_16x16x32_bf16(a, bfr[0][kb], acc2[0], 0, 0, 0);
        acc2[1] = __builtin_amdgcn_mfma_f32_16x16x32_bf16(a, bfr[1][kb], acc2[1], 0, 0, 0);
    }

#pragma unroll
    for (int ti = 0; ti < 2; ++ti) {
        int c = (wave * 2 + ti) * 16 + lm;
#pragma unroll
        for (int r = 0; r < 4; ++r) {
            int off = (p0 + q * 4 + r) * C_DIM + c;
            out[off] = acc2[ti][r] + bw[ti] + feats[off];
        }
    }
}

// ---------------------------------------------------------------- launch
extern "C" void kernel_launch(void* const* d_in, const int* in_sizes, int n_in,
                              void* d_out, int out_size, void* d_ws, size_t ws_size,
                              hipStream_t stream) {
    const float* coords = (const float*)d_in[0];
    const float* feats  = (const float*)d_in[1];
    const float* theta_w = (const float*)d_in[2];
    const float* theta_b = (const float*)d_in[3];
    const float* phi_w   = (const float*)d_in[4];
    const float* phi_b   = (const float*)d_in[5];
    const float* g_w     = (const float*)d_in[6];
    const float* g_b     = (const float*)d_in[7];
    const float* pe1_w1  = (const float*)d_in[8];
    const float* pe1_b1  = (const float*)d_in[9];
    const float* pe1_w2  = (const float*)d_in[10];
    const float* pe1_b2  = (const float*)d_in[11];
    const float* W_w     = (const float*)d_in[12];
    const float* W_b     = (const float*)d_in[13];
    float* out = (float*)d_out;

    char* w = (char*)d_ws;
    size_t off = 0;
    int* idx = (int*)(w + off);        off += (size_t)N_PTS * K_NN * 4;       // 512 KB
    bf16_t* fb = (bf16_t*)(w + off);   off += (size_t)N_PTS * C_DIM * 2;      // 4 MB
    bf16_t* wt = (bf16_t*)(w + off);   off += (size_t)5 * C_DIM * C_DIM * 2;  // 640 KB
    float* T = (float*)(w + off);      off += (size_t)N_PTS * C_DIM * 4;      // 8 MB
    bf16_t* PG = (bf16_t*)(w + off);   off += (size_t)N_PTS * C_DIM * 4;      // 8 MB (phi,g interleaved)
    // grid-KNN scratch (sp4 16B-aligned)
    float4* sp4 = (float4*)(w + off);  off += (size_t)N_PTS * 16;
    int* sidxp = (int*)(w + off);      off += (size_t)N_PTS * 4;
    int* cid       = (int*)(w + off);  off += (size_t)N_PTS * 4;
    int* cellCount = (int*)(w + off);  off += (size_t)GRID_NC * 4;
    int* cellStart = (int*)(w + off);  off += (size_t)(GRID_NC + 1) * 4;
    int* cellPtr   = (int*)(w + off);  off += (size_t)GRID_NC * 4;
    int* glist = (int*)(w + off);      off += (size_t)N_PTS * 4;
    int* gcount = (int*)(w + off);     off += 256;
    (void)ws_size; (void)in_sizes; (void)n_in; (void)out_size;

    prep_kernel<<<CAST_NBLK + PREPW_NBLK + 16, 256, 0, stream>>>(
        feats, fb, theta_w, phi_w, g_w, pe1_w2, W_w, wt, cellCount, gcount);

    grid_count_kernel<<<N_PTS / 256, 256, 0, stream>>>(coords, cellCount, cid);
    grid_scan_kernel<<<1, 256, 0, stream>>>(cellCount, cellStart, cellPtr);
    grid_scatter_kernel<<<N_PTS / 256, 256, 0, stream>>>(coords, cid, cellPtr, sp4, sidxp);
    knn_grid_kernel<<<N_PTS / 4, 256, 0, stream>>>(coords, cellStart, sp4, sidxp,
                                                   idx, glist, gcount);
    knn_fallback_kernel<<<32, 256, 0, stream>>>(coords, glist, gcount, idx);

    proj_kernel<<<dim3(N_PTS / 64, 3, 2), 256, 0, stream>>>(fb, wt, theta_b, phi_b, g_b, T, PG);
    pe2_fused_kernel<<<N_PTS / P_BLK, 512, 0, stream>>>(coords, idx, T, PG,
                                                        pe1_w1, pe1_b1, pe1_b2,
                                                        wt + 3 * C_DIM * C_DIM,
                                                        wt + 4 * C_DIM * C_DIM,
                                                        W_b, feats, out);
}

// Round 15
// 190.298 us; speedup vs baseline: 1.1942x; 1.1942x over previous
//
#include <hip/hip_runtime.h>

typedef __bf16 bf16_t;
typedef bf16_t bf16x8 __attribute__((ext_vector_type(8)));
typedef bf16_t bf16x4 __attribute__((ext_vector_type(4)));
typedef bf16_t bf16x2 __attribute__((ext_vector_type(2)));
typedef float f32x4 __attribute__((ext_vector_type(4)));
typedef unsigned long long u64;

#define N_PTS 8192
#define C_DIM 256
#define K_NN 16

// ---- spatial grid for exact KNN ----
#define GRID_G    16
#define GRID_NC   (GRID_G * GRID_G * GRID_G)   // 4096 cells
#define GRID_CELL 6.25f                        // 100 / 16
#define GRID_INV  0.16f                        // 16 / 100

// ---------------------------------------------------------------- prep (all-parallel, no long-pole block):
#define CAST_NBLK 2048
#define PREPW_NBLK 320
__global__ __launch_bounds__(256) void prep_kernel(
    const float* __restrict__ feats, bf16_t* __restrict__ fb,
    const float* __restrict__ w0, const float* __restrict__ w1,
    const float* __restrict__ w2, const float* __restrict__ w3,
    const float* __restrict__ w4, bf16_t* __restrict__ wt_base,
    int* __restrict__ cellCount, int* __restrict__ gcount) {
    const int b = blockIdx.x;
    const int t = threadIdx.x;

    if (b < CAST_NBLK) {
        int i = (b * 256 + t) * 4;
        float4 v = *(const float4*)(feats + i);
        bf16x4 o;
        o[0] = (bf16_t)v.x; o[1] = (bf16_t)v.y; o[2] = (bf16_t)v.z; o[3] = (bf16_t)v.w;
        *(bf16x4*)(fb + i) = o;
    } else if (b < CAST_NBLK + PREPW_NBLK) {
        int pb = b - CAST_NBLK;
        int m = pb >> 6;
        int bx = pb & 63;
        const float* src = (m == 0) ? w0 : (m == 1) ? w1 : (m == 2) ? w2 : (m == 3) ? w3 : w4;
        bf16_t* dst = wt_base + m * (C_DIM * C_DIM);
#pragma unroll
        for (int i = 0; i < 4; ++i) {
            int o = bx * 1024 + i * 256 + t;
            int tkb = o >> 9;
            int rem = o & 511;
            int lm = rem >> 5;
            int r = rem & 31;
            int k = (tkb & 7) * 32 + r;
            int n = (tkb >> 3) * 16 + lm;
            dst[o] = (bf16_t)src[k * C_DIM + n];
        }
    } else {
        int zb = b - CAST_NBLK - PREPW_NBLK;
        cellCount[zb * 256 + t] = 0;
        if (zb == 0 && t == 0) *gcount = 0;
    }
}

// ---------------------------------------------------------------- grid build: count per cell
__global__ __launch_bounds__(256) void grid_count_kernel(const float* __restrict__ coords,
                                                         int* __restrict__ cellCount,
                                                         int* __restrict__ cid) {
    int i = blockIdx.x * 256 + threadIdx.x;
    float x = coords[3 * i + 0], y = coords[3 * i + 1], z = coords[3 * i + 2];
    int cx = (int)(x * GRID_INV); if (cx > GRID_G - 1) cx = GRID_G - 1;
    int cy = (int)(y * GRID_INV); if (cy > GRID_G - 1) cy = GRID_G - 1;
    int cz = (int)(z * GRID_INV); if (cz > GRID_G - 1) cz = GRID_G - 1;
    int c = (cx * GRID_G + cy) * GRID_G + cz;
    cid[i] = c;
    atomicAdd(&cellCount[c], 1);
}

// ---------------------------------------------------------------- grid build: exclusive scan (1 block)
__global__ __launch_bounds__(256) void grid_scan_kernel(const int* __restrict__ cellCount,
                                                        int* __restrict__ cellStart,
                                                        int* __restrict__ cellPtr) {
    __shared__ int part[256];
    int t = threadIdx.x;
    int base = t * 16;
    int v[16];
    int sum = 0;
#pragma unroll
    for (int i = 0; i < 16; ++i) { v[i] = cellCount[base + i]; sum += v[i]; }
    part[t] = sum;
    __syncthreads();
    for (int off = 1; off < 256; off <<= 1) {
        int x = (t >= off) ? part[t - off] : 0;
        __syncthreads();
        part[t] += x;
        __syncthreads();
    }
    int acc = part[t] - sum;
#pragma unroll
    for (int i = 0; i < 16; ++i) {
        cellStart[base + i] = acc;
        cellPtr[base + i] = acc;
        acc += v[i];
    }
    if (t == 255) cellStart[GRID_NC] = acc;
}

// ---------------------------------------------------------------- grid build: scatter into sorted float4 plane
__global__ __launch_bounds__(256) void grid_scatter_kernel(
    const float* __restrict__ coords, const int* __restrict__ cid, int* __restrict__ cellPtr,
    float4* __restrict__ sp4, int* __restrict__ sidx) {
    int i = blockIdx.x * 256 + threadIdx.x;
    int c = cid[i];
    int pos = atomicAdd(&cellPtr[c], 1);
    float x = coords[3 * i + 0], y = coords[3 * i + 1], z = coords[3 * i + 2];
    // exact same bit sequence as reference sq:
    float sq = __fadd_rn(__fadd_rn(__fmul_rn(x, x), __fmul_rn(y, y)), __fmul_rn(z, z));
    sp4[pos] = make_float4(x, y, z, sq);
    sidx[pos] = i;
}

// ---------------------------------------------------------------- KNN via grid window (1 wave per query)
__global__ __launch_bounds__(256) void knn_grid_kernel(
    const float* __restrict__ coords, const int* __restrict__ cellStart,
    const float4* __restrict__ sp4, const int* __restrict__ sidx,
    int* __restrict__ idx_out, int* __restrict__ glist, int* __restrict__ gcount) {
    const int tid = threadIdx.x;
    const int wave = tid >> 6, lane = tid & 63;
    const int q = blockIdx.x * 4 + wave;

    __shared__ int segBase[4][25];
    __shared__ int segPref[4][26];

    const float qx = coords[3 * q + 0], qy = coords[3 * q + 1], qz = coords[3 * q + 2];
    const float sqi = __fadd_rn(__fadd_rn(__fmul_rn(qx, qx), __fmul_rn(qy, qy)),
                                __fmul_rn(qz, qz));

    int cx = (int)(qx * GRID_INV); if (cx > GRID_G - 1) cx = GRID_G - 1;
    int cy = (int)(qy * GRID_INV); if (cy > GRID_G - 1) cy = GRID_G - 1;
    int cz = (int)(qz * GRID_INV); if (cz > GRID_G - 1) cz = GRID_G - 1;
    int wx0 = cx - 2; if (wx0 < 0) wx0 = 0;
    int wx1 = cx + 2; if (wx1 > GRID_G - 1) wx1 = GRID_G - 1;
    int wy0 = cy - 2; if (wy0 < 0) wy0 = 0;
    int wy1 = cy + 2; if (wy1 > GRID_G - 1) wy1 = GRID_G - 1;
    int wz0 = cz - 2; if (wz0 < 0) wz0 = 0;
    int wz1 = cz + 2; if (wz1 > GRID_G - 1) wz1 = GRID_G - 1;

    const float INF = __int_as_float(0x7f800000);
    float rc = INF;
    if (wx0 > 0)          rc = fminf(rc, qx - (float)wx0 * GRID_CELL);
    if (wx1 < GRID_G - 1) rc = fminf(rc, (float)(wx1 + 1) * GRID_CELL - qx);
    if (wy0 > 0)          rc = fminf(rc, qy - (float)wy0 * GRID_CELL);
    if (wy1 < GRID_G - 1) rc = fminf(rc, (float)(wy1 + 1) * GRID_CELL - qy);
    if (wz0 > 0)          rc = fminf(rc, qz - (float)wz0 * GRID_CELL);
    if (wz1 < GRID_G - 1) rc = fminf(rc, (float)(wz1 + 1) * GRID_CELL - qz);
    float rc2 = rc * rc * 0.9999f;

    int nx = wx1 - wx0 + 1, nyc = wy1 - wy0 + 1;
    int ns = nx * nyc;
    if (lane < ns) {
        int scx = wx0 + lane / nyc;
        int scy = wy0 + lane % nyc;
        int b = (scx * GRID_G + scy) * GRID_G;
        int s0 = cellStart[b + wz0];
        int s1 = cellStart[b + wz1 + 1];
        segBase[wave][lane] = s0;
        segPref[wave][lane] = s1 - s0;
    }
    __syncthreads();
    if (lane == 0) {
        int acc = 0;
        for (int s = 0; s < ns; ++s) { int l = segPref[wave][s]; segPref[wave][s] = acc; acc += l; }
        segPref[wave][ns] = acc;
    }
    __syncthreads();

    const int M = segPref[wave][ns];
    bool flag = (M < K_NN) || (M > 320);

    // ---- load up to 5 keys per lane directly from the window (static slot indexing)
    u64 k0 = ~0ull, k1 = ~0ull, k2 = ~0ull, k3 = ~0ull, k4 = ~0ull;
    {
        int s = 0;
#pragma unroll
        for (int slot = 0; slot < 5; ++slot) {
            int t = lane + slot * 64;
            if (t < M) {
                while (t >= segPref[wave][s + 1]) ++s;
                int pos = segBase[wave][s] + (t - segPref[wave][s]);
                float4 v = sp4[pos];
                float dot = __fmaf_rn(v.z, qz, __fmaf_rn(v.y, qy, __fmul_rn(v.x, qx)));
                float d2 = __fsub_rn(__fadd_rn(sqi, v.w), __fmul_rn(2.0f, dot));
                unsigned u = __float_as_uint(d2);
                u = (u & 0x80000000u) ? ~u : (u | 0x80000000u);
                u64 key = (((u64)u) << 32) | (unsigned)sidx[pos];
                if (slot == 0) k0 = key;
                else if (slot == 1) k1 = key;
                else if (slot == 2) k2 = key;
                else if (slot == 3) k3 = key;
                else k4 = key;
            }
        }
    }

    // ---- selection: 16 wave-argmin rounds over unique (d2, idx) keys
    u64 lm2 = k0; int li = 0;
    if (k1 < lm2) { lm2 = k1; li = 1; }
    if (k2 < lm2) { lm2 = k2; li = 2; }
    if (k3 < lm2) { lm2 = k3; li = 3; }
    if (k4 < lm2) { lm2 = k4; li = 4; }
    int keep = 0;
    u64 last = ~0ull;
#pragma unroll 1
    for (int r = 0; r < 16; ++r) {
        u64 w = lm2;
#pragma unroll
        for (int off = 1; off < 64; off <<= 1) {
            u64 o = __shfl_xor(w, off);
            w = (o < w) ? o : w;
        }
        if (lane == r) keep = (int)(unsigned)(w & 0xffffffffull);
        last = w;
        if (lm2 == w) {  // unique winner: retire slot, recompute local min
            if (li == 0) k0 = ~0ull;
            else if (li == 1) k1 = ~0ull;
            else if (li == 2) k2 = ~0ull;
            else if (li == 3) k3 = ~0ull;
            else k4 = ~0ull;
            lm2 = k0; li = 0;
            if (k1 < lm2) { lm2 = k1; li = 1; }
            if (k2 < lm2) { lm2 = k2; li = 2; }
            if (k3 < lm2) { lm2 = k3; li = 3; }
            if (k4 < lm2) { lm2 = k4; li = 4; }
        }
    }

    // ---- coverage check on exact d16
    if (!flag) {
        unsigned ou = (unsigned)(last >> 32);
        unsigned db = (ou & 0x80000000u) ? (ou ^ 0x80000000u) : ~ou;
        float d16 = __uint_as_float(db);
        if (d16 >= rc2) flag = true;
    }
    if (flag && lane == 0) {
        int sl = atomicAdd(gcount, 1);
        glist[sl] = q;
    }
    if (lane < 16) idx_out[q * K_NN + lane] = keep;   // flagged queries overwritten by fallback
}

// ---------------------------------------------------------------- KNN brute-force fallback for flagged queries
// Grid-stride over glist (32 blocks; ~40 flagged queries expected).
__global__ __launch_bounds__(256) void knn_fallback_kernel(const float* __restrict__ coords,
                                                           const int* __restrict__ glist,
                                                           const int* __restrict__ gcount,
                                                           int* __restrict__ idx_out) {
    const int count = *gcount;
    const int tid = threadIdx.x;
    const int wave = tid >> 6, lane = tid & 63;
    __shared__ float red16[4][16];
    __shared__ u64 cand[4][256];
    __shared__ int cnt[4];
    __shared__ int qids[4];
    const float INF = __int_as_float(0x7f800000);
    const float* cp = coords + tid * 96;

#pragma unroll 1
    for (int n0 = blockIdx.x * 4; n0 < count; n0 += gridDim.x * 4) {
        if (tid < 4) {
            cnt[tid] = 0;
            int slot = n0 + tid;
            qids[tid] = glist[slot < count ? slot : count - 1];
        }
        __syncthreads();

        float qx[4], qy[4], qz[4], sqi[4];
#pragma unroll
        for (int q = 0; q < 4; ++q) {
            int id = qids[q];
            qx[q] = coords[3 * id + 0];
            qy[q] = coords[3 * id + 1];
            qz[q] = coords[3 * id + 2];
            sqi[q] = __fadd_rn(__fadd_rn(__fmul_rn(qx[q], qx[q]), __fmul_rn(qy[q], qy[q])),
                               __fmul_rn(qz[q], qz[q]));
        }

        float lmin[4] = {INF, INF, INF, INF};
#pragma unroll
        for (int c = 0; c < 4; ++c) {
            float buf[24];
#pragma unroll
            for (int v = 0; v < 6; ++v)
                *(float4*)(buf + v * 4) = *(const float4*)(cp + c * 24 + v * 4);
#pragma unroll
            for (int p = 0; p < 8; ++p) {
                float x = buf[3 * p + 0], y = buf[3 * p + 1], z = buf[3 * p + 2];
                float sqj = __fadd_rn(__fadd_rn(__fmul_rn(x, x), __fmul_rn(y, y)),
                                      __fmul_rn(z, z));
#pragma unroll
                for (int q = 0; q < 4; ++q) {
                    float dot = __fmaf_rn(z, qz[q], __fmaf_rn(y, qy[q], __fmul_rn(x, qx[q])));
                    float d2 = __fsub_rn(__fadd_rn(sqi[q], sqj), __fmul_rn(2.0f, dot));
                    lmin[q] = fminf(lmin[q], d2);
                }
            }
        }

#pragma unroll
        for (int q = 0; q < 4; ++q) {
            float g = lmin[q];
            g = fminf(g, __shfl_xor(g, 1));
            g = fminf(g, __shfl_xor(g, 2));
            g = fminf(g, __shfl_xor(g, 4));
            g = fminf(g, __shfl_xor(g, 8));
            if ((lane & 15) == 0) red16[q][wave * 4 + (lane >> 4)] = g;
        }
        __syncthreads();

        float tau[4];
#pragma unroll
        for (int q = 0; q < 4; ++q) {
            float t = red16[q][0];
#pragma unroll
            for (int i = 1; i < 16; ++i) t = fmaxf(t, red16[q][i]);
            tau[q] = t;
        }

#pragma unroll
        for (int c = 0; c < 4; ++c) {
            float buf[24];
#pragma unroll
            for (int v = 0; v < 6; ++v)
                *(float4*)(buf + v * 4) = *(const float4*)(cp + c * 24 + v * 4);
#pragma unroll
            for (int p = 0; p < 8; ++p) {
                float x = buf[3 * p + 0], y = buf[3 * p + 1], z = buf[3 * p + 2];
                float sqj = __fadd_rn(__fadd_rn(__fmul_rn(x, x), __fmul_rn(y, y)),
                                      __fmul_rn(z, z));
                int j = tid * 32 + c * 8 + p;
#pragma unroll
                for (int q = 0; q < 4; ++q) {
                    float dot = __fmaf_rn(z, qz[q], __fmaf_rn(y, qy[q], __fmul_rn(x, qx[q])));
                    float d2 = __fsub_rn(__fadd_rn(sqi[q], sqj), __fmul_rn(2.0f, dot));
                    if (d2 <= tau[q]) {
                        unsigned u = __float_as_uint(d2);
                        u = (u & 0x80000000u) ? ~u : (u | 0x80000000u);
                        int slot = atomicAdd(&cnt[q], 1);
                        if (slot < 256)
                            cand[q][slot] = (((u64)u) << 32) | (unsigned)j;
                    }
                }
            }
        }
        __syncthreads();

        int m = cnt[wave]; if (m > 256) m = 256;
        u64 k0 = ~0ull, k1 = ~0ull, k2 = ~0ull, k3 = ~0ull;
        if (lane < m) k0 = cand[wave][lane];
        if (lane + 64 < m) k1 = cand[wave][lane + 64];
        if (lane + 128 < m) k2 = cand[wave][lane + 128];
        if (lane + 192 < m) k3 = cand[wave][lane + 192];
        u64 lm2 = k0; int li = 0;
        if (k1 < lm2) { lm2 = k1; li = 1; }
        if (k2 < lm2) { lm2 = k2; li = 2; }
        if (k3 < lm2) { lm2 = k3; li = 3; }
        int keep = 0;
#pragma unroll 1
        for (int r = 0; r < 16; ++r) {
            u64 w = lm2;
#pragma unroll
            for (int off = 1; off < 64; off <<= 1) {
                u64 o = __shfl_xor(w, off);
                w = (o < w) ? o : w;
            }
            if (lane == r) keep = (int)(unsigned)(w & 0xffffffffull);
            if (lm2 == w) {
                if (li == 0) k0 = ~0ull;
                else if (li == 1) k1 = ~0ull;
                else if (li == 2) k2 = ~0ull;
                else k3 = ~0ull;
                lm2 = k0; li = 0;
                if (k1 < lm2) { lm2 = k1; li = 1; }
                if (k2 < lm2) { lm2 = k2; li = 2; }
                if (k3 < lm2) { lm2 = k3; li = 3; }
            }
        }
        if (n0 + wave < count && lane < 16)
            idx_out[qids[wave] * K_NN + lane] = keep;
        __syncthreads();   // cand/cnt reuse safe before next grid-stride iteration
    }
}

// ---------------------------------------------------------------- proj: T/PG = feats@{theta,phi,g}+b
__global__ __launch_bounds__(256, 2) void proj_kernel(
    const bf16_t* __restrict__ fb, const bf16_t* __restrict__ wt_base,
    const float* __restrict__ tb, const float* __restrict__ pb, const float* __restrict__ gb,
    float* __restrict__ T, bf16_t* __restrict__ PG) {
    const int sel = blockIdx.y;
    const int half = blockIdx.z;
    const bf16_t* Wt = wt_base + sel * (C_DIM * C_DIM);
    const float* bias = (sel == 0) ? tb : (sel == 1) ? pb : gb;
    const int wave = threadIdx.x >> 6, lane = threadIdx.x & 63;
    const int q = lane >> 4, lm = lane & 15;
    const int m0 = blockIdx.x * 64;

    bf16x8 bfr[2][8];
#pragma unroll
    for (int ti = 0; ti < 2; ++ti)
#pragma unroll
        for (int kb = 0; kb < 8; ++kb)
            bfr[ti][kb] = *(const bf16x8*)(Wt + (((half * 8 + wave * 2 + ti) * 8 + kb) << 9) + lm * 32 + q * 8);

    float bv[2];
#pragma unroll
    for (int ti = 0; ti < 2; ++ti) bv[ti] = bias[(half * 8 + wave * 2 + ti) * 16 + lm];

#pragma unroll
    for (int p = 0; p < 4; ++p) {
        const bf16_t* arow = fb + (m0 + p * 16 + lm) * C_DIM + q * 8;
        f32x4 acc[2];
        acc[0] = (f32x4){0.f, 0.f, 0.f, 0.f};
        acc[1] = (f32x4){0.f, 0.f, 0.f, 0.f};
#pragma unroll
        for (int kb = 0; kb < 8; ++kb) {
            bf16x8 a = *(const bf16x8*)(arow + kb * 32);
            acc[0] = __builtin_amdgcn_mfma_f32_16x16x32_bf16(a, bfr[0][kb], acc[0], 0, 0, 0);
            acc[1] = __builtin_amdgcn_mfma_f32_16x16x32_bf16(a, bfr[1][kb], acc[1], 0, 0, 0);
        }

#pragma unroll
        for (int ti = 0; ti < 2; ++ti) {
            int c = (half * 8 + wave * 2 + ti) * 16 + lm;
#pragma unroll
            for (int r = 0; r < 4; ++r) {
                float v = acc[ti][r] + bv[ti];
                int off = (m0 + p * 16 + q * 4 + r) * C_DIM + c;
                if (sel == 0) T[off] = v;
                else if (sel == 1) PG[2 * off] = (bf16_t)v;
                else PG[2 * off + 1] = (bf16_t)v;
            }
        }
    }
}

// ---------------------------------------------------------------- pe1 + pe2 GEMM + softmax + weighted G-sum
//                                                                  + fused FINAL GEMM (out = y@W_w + W_b + feats)
// 512-thread / 8-wave, __launch_bounds__(512,4). Round-12 loop body (gathers
// issued inline at lp start -- proven 48.7us, zero spills; rounds 13/14 showed
// cross-barrier gather prefetch always spills or is drained at the barrier) +
// round-13's fused final GEMM (neutral-positive: removes yb round-trip + launch).
#define HPAD 264
#define P_BLK 16
#define HROWS (P_BLK * 16)
__global__ __launch_bounds__(512, 4) void pe2_fused_kernel(
    const float* __restrict__ coords, const int* __restrict__ idx,
    const float* __restrict__ T, const bf16_t* __restrict__ PG,
    const float* __restrict__ w1, const float* __restrict__ b1, const float* __restrict__ b2,
    const bf16_t* __restrict__ Wt2, const bf16_t* __restrict__ Wt3,
    const float* __restrict__ Wb, const float* __restrict__ feats,
    float* __restrict__ out) {
    __shared__ __align__(16) bf16_t hbuf[2][16 * HPAD];
    __shared__ __align__(16) bf16_t yl[16][HPAD];
    __shared__ float dxyz[HROWS][3];
    __shared__ int idxl[HROWS];
    const int tid = threadIdx.x;
    const int p0 = blockIdx.x * P_BLK;
    const int wave = tid >> 6, lane = tid & 63;
    const int q = lane >> 4, lm = lane & 15;

    // 2 col-tiles per wave; global tile index t = wave*2 + ti (0..15)
    bf16x8 bfr[2][8];
#pragma unroll
    for (int ti = 0; ti < 2; ++ti)
#pragma unroll
        for (int kb = 0; kb < 8; ++kb)
            bfr[ti][kb] = *(const bf16x8*)(Wt2 + (((wave * 2 + ti) * 8 + kb) << 9) + lm * 32 + q * 8);
    float b2c[2];
#pragma unroll
    for (int ti = 0; ti < 2; ++ti) b2c[ti] = b2[(wave * 2 + ti) * 16 + lm];

    if (tid < HROWS) {
        int n = p0 + (tid >> 4);
        int j = idx[n * K_NN + (tid & 15)];
        idxl[tid] = j;
        dxyz[tid][0] = coords[3 * j + 0] - coords[3 * n + 0];
        dxyz[tid][1] = coords[3 * j + 1] - coords[3 * n + 1];
        dxyz[tid][2] = coords[3 * j + 2] - coords[3 * n + 2];
    }
    __syncthreads();

    // pe1: thread handles column hc, rows rh..rh+7 of each 16-row tile
    const int hc = tid & 255;
    const int rh = (tid >> 8) * 8;
    const float wx = w1[hc], wy = w1[C_DIM + hc], wz = w1[2 * C_DIM + hc], bb = b1[hc];

    // prologue: stage h rows for lp=0 into buf 0
#pragma unroll
    for (int r = 0; r < 8; ++r) {
        int row = rh + r;
        float pre = dxyz[row][0] * wx + dxyz[row][1] * wy + dxyz[row][2] * wz + bb;
        hbuf[0][row * HPAD + hc] = (bf16_t)fmaxf(pre, 0.0f);
    }
    __syncthreads();

#pragma unroll 1
    for (int lp = 0; lp < P_BLK; ++lp) {
        const int n = p0 + lp;
        const int cur = lp & 1;

        // ---- issue (phi,g) + T gathers first; h-compute + MFMA hide their latency
        int jr[4];
#pragma unroll
        for (int r = 0; r < 4; ++r) jr[r] = idxl[lp * 16 + q * 4 + r];
        bf16x2 pg[2][4];
        float Tn[2];
#pragma unroll
        for (int ti = 0; ti < 2; ++ti) {
            int c = (wave * 2 + ti) * 16 + lm;
            Tn[ti] = T[n * C_DIM + c];
#pragma unroll
            for (int r = 0; r < 4; ++r)
                pg[ti][r] = *(const bf16x2*)(PG + 2 * (jr[r] * C_DIM + c));
        }

        // ---- stage h for lp+1 into the other buffer (VALU work = gather cover)
        if (lp + 1 < P_BLK) {
            int rb = (lp + 1) * 16;
#pragma unroll
            for (int r = 0; r < 8; ++r) {
                int row = rh + r;
                float pre = dxyz[rb + row][0] * wx + dxyz[rb + row][1] * wy
                          + dxyz[rb + row][2] * wz + bb;
                hbuf[cur ^ 1][row * HPAD + hc] = (bf16_t)fmaxf(pre, 0.0f);
            }
        }

        // ---- pe2 GEMM: stream a per-kb (short live range), 2 MFMAs per kb
        const bf16_t* hrow = &hbuf[cur][lm * HPAD + q * 8];
        f32x4 acc[2];
        acc[0] = (f32x4){0.f, 0.f, 0.f, 0.f};
        acc[1] = (f32x4){0.f, 0.f, 0.f, 0.f};
#pragma unroll
        for (int kb = 0; kb < 8; ++kb) {
            bf16x8 a = *(const bf16x8*)(hrow + kb * 32);
            acc[0] = __builtin_amdgcn_mfma_f32_16x16x32_bf16(a, bfr[0][kb], acc[0], 0, 0, 0);
            acc[1] = __builtin_amdgcn_mfma_f32_16x16x32_bf16(a, bfr[1][kb], acc[1], 0, 0, 0);
        }

#pragma unroll
        for (int ti = 0; ti < 2; ++ti) {
            int c = (wave * 2 + ti) * 16 + lm;
            float df[4];
#pragma unroll
            for (int r = 0; r < 4; ++r) {
                float pe = acc[ti][r] + b2c[ti];
                df[r] = (pe * (Tn[ti] - (float)pg[ti][r][0]) + pe) * 0.0625f;
            }
            float mx = fmaxf(fmaxf(df[0], df[1]), fmaxf(df[2], df[3]));
            mx = fmaxf(mx, __shfl_xor(mx, 16));
            mx = fmaxf(mx, __shfl_xor(mx, 32));
            float e[4], s = 0.f;
#pragma unroll
            for (int r = 0; r < 4; ++r) { e[r] = __expf(df[r] - mx); s += e[r]; }
            s += __shfl_xor(s, 16);
            s += __shfl_xor(s, 32);
            float inv = 1.0f / s;
            float y = 0.f;
#pragma unroll
            for (int r = 0; r < 4; ++r) y += e[r] * inv * (float)pg[ti][r][1];
            y += __shfl_xor(y, 16);
            y += __shfl_xor(y, 32);
            if (q == 0) yl[lp][c] = (bf16_t)y;
        }
        __syncthreads();   // hbuf[cur^1] + yl[lp] writes visible
    }

    // ---- fused final GEMM: out[p0..p0+15] = y @ W_w + W_b + feats
#pragma unroll
    for (int ti = 0; ti < 2; ++ti)
#pragma unroll
        for (int kb = 0; kb < 8; ++kb)
            bfr[ti][kb] = *(const bf16x8*)(Wt3 + (((wave * 2 + ti) * 8 + kb) << 9) + lm * 32 + q * 8);
    float bw[2];
#pragma unroll
    for (int ti = 0; ti < 2; ++ti) bw[ti] = Wb[(wave * 2 + ti) * 16 + lm];

    f32x4 acc2[2];
    acc2[0] = (f32x4){0.f, 0.f, 0.f, 0.f};
    acc2[1] = (f32x4){0.f, 0.f, 0.f, 0.f};
#pragma unroll
    for (int kb = 0; kb < 8; ++kb) {
        bf16x8 a = *(const bf16x8*)(&yl[lm][kb * 32 + q * 8]);
        acc2[0] = __builtin_amdgcn_mfma_f32_16x16x32_bf16(a, bfr[0][kb], acc2[0], 0, 0, 0);
        acc2[1] = __builtin_amdgcn_mfma_f32_16x16x32_bf16(a, bfr[1][kb], acc2[1], 0, 0, 0);
    }

#pragma unroll
    for (int ti = 0; ti < 2; ++ti) {
        int c = (wave * 2 + ti) * 16 + lm;
#pragma unroll
        for (int r = 0; r < 4; ++r) {
            int off = (p0 + q * 4 + r) * C_DIM + c;
            out[off] = acc2[ti][r] + bw[ti] + feats[off];
        }
    }
}

// ---------------------------------------------------------------- launch
extern "C" void kernel_launch(void* const* d_in, const int* in_sizes, int n_in,
                              void* d_out, int out_size, void* d_ws, size_t ws_size,
                              hipStream_t stream) {
    const float* coords = (const float*)d_in[0];
    const float* feats  = (const float*)d_in[1];
    const float* theta_w = (const float*)d_in[2];
    const float* theta_b = (const float*)d_in[3];
    const float* phi_w   = (const float*)d_in[4];
    const float* phi_b   = (const float*)d_in[5];
    const float* g_w     = (const float*)d_in[6];
    const float* g_b     = (const float*)d_in[7];
    const float* pe1_w1  = (const float*)d_in[8];
    const float* pe1_b1  = (const float*)d_in[9];
    const float* pe1_w2  = (const float*)d_in[10];
    const float* pe1_b2  = (const float*)d_in[11];
    const float* W_w     = (const float*)d_in[12];
    const float* W_b     = (const float*)d_in[13];
    float* out = (float*)d_out;

    char* w = (char*)d_ws;
    size_t off = 0;
    int* idx = (int*)(w + off);        off += (size_t)N_PTS * K_NN * 4;       // 512 KB
    bf16_t* fb = (bf16_t*)(w + off);   off += (size_t)N_PTS * C_DIM * 2;      // 4 MB
    bf16_t* wt = (bf16_t*)(w + off);   off += (size_t)5 * C_DIM * C_DIM * 2;  // 640 KB
    float* T = (float*)(w + off);      off += (size_t)N_PTS * C_DIM * 4;      // 8 MB
    bf16_t* PG = (bf16_t*)(w + off);   off += (size_t)N_PTS * C_DIM * 4;      // 8 MB (phi,g interleaved)
    // grid-KNN scratch (sp4 16B-aligned)
    float4* sp4 = (float4*)(w + off);  off += (size_t)N_PTS * 16;
    int* sidxp = (int*)(w + off);      off += (size_t)N_PTS * 4;
    int* cid       = (int*)(w + off);  off += (size_t)N_PTS * 4;
    int* cellCount = (int*)(w + off);  off += (size_t)GRID_NC * 4;
    int* cellStart = (int*)(w + off);  off += (size_t)(GRID_NC + 1) * 4;
    int* cellPtr   = (int*)(w + off);  off += (size_t)GRID_NC * 4;
    int* glist = (int*)(w + off);      off += (size_t)N_PTS * 4;
    int* gcount = (int*)(w + off);     off += 256;
    (void)ws_size; (void)in_sizes; (void)n_in; (void)out_size;

    prep_kernel<<<CAST_NBLK + PREPW_NBLK + 16, 256, 0, stream>>>(
        feats, fb, theta_w, phi_w, g_w, pe1_w2, W_w, wt, cellCount, gcount);

    grid_count_kernel<<<N_PTS / 256, 256, 0, stream>>>(coords, cellCount, cid);
    grid_scan_kernel<<<1, 256, 0, stream>>>(cellCount, cellStart, cellPtr);
    grid_scatter_kernel<<<N_PTS / 256, 256, 0, stream>>>(coords, cid, cellPtr, sp4, sidxp);
    knn_grid_kernel<<<N_PTS / 4, 256, 0, stream>>>(coords, cellStart, sp4, sidxp,
                                                   idx, glist, gcount);
    knn_fallback_kernel<<<32, 256, 0, stream>>>(coords, glist, gcount, idx);

    proj_kernel<<<dim3(N_PTS / 64, 3, 2), 256, 0, stream>>>(fb, wt, theta_b, phi_b, g_b, T, PG);
    pe2_fused_kernel<<<N_PTS / P_BLK, 512, 0, stream>>>(coords, idx, T, PG,
                                                        pe1_w1, pe1_b1, pe1_b2,
                                                        wt + 3 * C_DIM * C_DIM,
                                                        wt + 4 * C_DIM * C_DIM,
                                                        W_b, feats, out);
}

// Round 17
// 187.883 us; speedup vs baseline: 1.2095x; 1.0129x over previous
//
#include <hip/hip_runtime.h>

typedef __bf16 bf16_t;
typedef bf16_t bf16x8 __attribute__((ext_vector_type(8)));
typedef bf16_t bf16x4 __attribute__((ext_vector_type(4)));
typedef bf16_t bf16x2 __attribute__((ext_vector_type(2)));
typedef float f32x4 __attribute__((ext_vector_type(4)));
typedef unsigned long long u64;

#define N_PTS 8192
#define C_DIM 256
#define K_NN 16

// ---- spatial grid for exact KNN ----
#define GRID_G    16
#define GRID_NC   (GRID_G * GRID_G * GRID_G)   // 4096 cells
#define GRID_CELL 6.25f                        // 100 / 16
#define GRID_INV  0.16f                        // 16 / 100

// ---------------------------------------------------------------- prep (all-parallel, no long-pole block):
#define CAST_NBLK 2048
#define PREPW_NBLK 320
__global__ __launch_bounds__(256) void prep_kernel(
    const float* __restrict__ feats, bf16_t* __restrict__ fb,
    const float* __restrict__ w0, const float* __restrict__ w1,
    const float* __restrict__ w2, const float* __restrict__ w3,
    const float* __restrict__ w4, bf16_t* __restrict__ wt_base,
    int* __restrict__ cellCount, int* __restrict__ gcount) {
    const int b = blockIdx.x;
    const int t = threadIdx.x;

    if (b < CAST_NBLK) {
        int i = (b * 256 + t) * 4;
        float4 v = *(const float4*)(feats + i);
        bf16x4 o;
        o[0] = (bf16_t)v.x; o[1] = (bf16_t)v.y; o[2] = (bf16_t)v.z; o[3] = (bf16_t)v.w;
        *(bf16x4*)(fb + i) = o;
    } else if (b < CAST_NBLK + PREPW_NBLK) {
        int pblk = b - CAST_NBLK;
        int m = pblk >> 6;
        int bx = pblk & 63;
        const float* src = (m == 0) ? w0 : (m == 1) ? w1 : (m == 2) ? w2 : (m == 3) ? w3 : w4;
        bf16_t* dst = wt_base + m * (C_DIM * C_DIM);
#pragma unroll
        for (int i = 0; i < 4; ++i) {
            int o = bx * 1024 + i * 256 + t;
            int tkb = o >> 9;
            int rem = o & 511;
            int lm = rem >> 5;
            int r = rem & 31;
            int k = (tkb & 7) * 32 + r;
            int n = (tkb >> 3) * 16 + lm;
            dst[o] = (bf16_t)src[k * C_DIM + n];
        }
    } else {
        int zb = b - CAST_NBLK - PREPW_NBLK;
        cellCount[zb * 256 + t] = 0;
        if (zb == 0 && t == 0) *gcount = 0;
    }
}

// ---------------------------------------------------------------- grid build: count per cell
__global__ __launch_bounds__(256) void grid_count_kernel(const float* __restrict__ coords,
                                                         int* __restrict__ cellCount,
                                                         int* __restrict__ cid) {
    int i = blockIdx.x * 256 + threadIdx.x;
    float x = coords[3 * i + 0], y = coords[3 * i + 1], z = coords[3 * i + 2];
    int cx = (int)(x * GRID_INV); if (cx > GRID_G - 1) cx = GRID_G - 1;
    int cy = (int)(y * GRID_INV); if (cy > GRID_G - 1) cy = GRID_G - 1;
    int cz = (int)(z * GRID_INV); if (cz > GRID_G - 1) cz = GRID_G - 1;
    int c = (cx * GRID_G + cy) * GRID_G + cz;
    cid[i] = c;
    atomicAdd(&cellCount[c], 1);
}

// ---------------------------------------------------------------- grid build: exclusive scan (1 block)
__global__ __launch_bounds__(256) void grid_scan_kernel(const int* __restrict__ cellCount,
                                                        int* __restrict__ cellStart,
                                                        int* __restrict__ cellPtr) {
    __shared__ int part[256];
    int t = threadIdx.x;
    int base = t * 16;
    int v[16];
    int sum = 0;
#pragma unroll
    for (int i = 0; i < 16; ++i) { v[i] = cellCount[base + i]; sum += v[i]; }
    part[t] = sum;
    __syncthreads();
    for (int off = 1; off < 256; off <<= 1) {
        int x = (t >= off) ? part[t - off] : 0;
        __syncthreads();
        part[t] += x;
        __syncthreads();
    }
    int acc = part[t] - sum;
#pragma unroll
    for (int i = 0; i < 16; ++i) {
        cellStart[base + i] = acc;
        cellPtr[base + i] = acc;
        acc += v[i];
    }
    if (t == 255) cellStart[GRID_NC] = acc;
}

// ---------------------------------------------------------------- grid build: scatter into sorted float4 plane
__global__ __launch_bounds__(256) void grid_scatter_kernel(
    const float* __restrict__ coords, const int* __restrict__ cid, int* __restrict__ cellPtr,
    float4* __restrict__ sp4, int* __restrict__ sidx) {
    int i = blockIdx.x * 256 + threadIdx.x;
    int c = cid[i];
    int pos = atomicAdd(&cellPtr[c], 1);
    float x = coords[3 * i + 0], y = coords[3 * i + 1], z = coords[3 * i + 2];
    // exact same bit sequence as reference sq:
    float sq = __fadd_rn(__fadd_rn(__fmul_rn(x, x), __fmul_rn(y, y)), __fmul_rn(z, z));
    sp4[pos] = make_float4(x, y, z, sq);
    sidx[pos] = i;
}

// ---------------------------------------------------------------- MERGED: knn_grid (blocks [0,2048)) + proj (blocks [2048,2816))
// Independent workloads co-dispatched so latency-bound KNN waves (0% MFMA) and
// MFMA-bound proj waves overlap on the CUs (m114: separate pipes, time ~= max).
// Whole blocks take one branch -> no divergence; footprint = max of the two.
#define KNN_NBLK (N_PTS / 4)
#define PROJ_NBLK (128 * 3 * 2)
__global__ __launch_bounds__(256) void knn_proj_kernel(
    const float* __restrict__ coords, const int* __restrict__ cellStart,
    const float4* __restrict__ sp4, const int* __restrict__ sidx,
    int* __restrict__ idx_out, int* __restrict__ glist, int* __restrict__ gcount,
    const bf16_t* __restrict__ fb, const bf16_t* __restrict__ wt_base,
    const float* __restrict__ tb, const float* __restrict__ phb, const float* __restrict__ gb,
    float* __restrict__ T, bf16_t* __restrict__ PG) {
    const int tid = threadIdx.x;
    const int wave = tid >> 6, lane = tid & 63;

    __shared__ int segBase[4][25];
    __shared__ int segPref[4][26];

    if (blockIdx.x < KNN_NBLK) {
        // ================= KNN via grid window (1 wave per query) =================
        const int q = blockIdx.x * 4 + wave;

        const float qx = coords[3 * q + 0], qy = coords[3 * q + 1], qz = coords[3 * q + 2];
        const float sqi = __fadd_rn(__fadd_rn(__fmul_rn(qx, qx), __fmul_rn(qy, qy)),
                                    __fmul_rn(qz, qz));

        int cx = (int)(qx * GRID_INV); if (cx > GRID_G - 1) cx = GRID_G - 1;
        int cy = (int)(qy * GRID_INV); if (cy > GRID_G - 1) cy = GRID_G - 1;
        int cz = (int)(qz * GRID_INV); if (cz > GRID_G - 1) cz = GRID_G - 1;
        int wx0 = cx - 2; if (wx0 < 0) wx0 = 0;
        int wx1 = cx + 2; if (wx1 > GRID_G - 1) wx1 = GRID_G - 1;
        int wy0 = cy - 2; if (wy0 < 0) wy0 = 0;
        int wy1 = cy + 2; if (wy1 > GRID_G - 1) wy1 = GRID_G - 1;
        int wz0 = cz - 2; if (wz0 < 0) wz0 = 0;
        int wz1 = cz + 2; if (wz1 > GRID_G - 1) wz1 = GRID_G - 1;

        const float INF = __int_as_float(0x7f800000);
        float rc = INF;
        if (wx0 > 0)          rc = fminf(rc, qx - (float)wx0 * GRID_CELL);
        if (wx1 < GRID_G - 1) rc = fminf(rc, (float)(wx1 + 1) * GRID_CELL - qx);
        if (wy0 > 0)          rc = fminf(rc, qy - (float)wy0 * GRID_CELL);
        if (wy1 < GRID_G - 1) rc = fminf(rc, (float)(wy1 + 1) * GRID_CELL - qy);
        if (wz0 > 0)          rc = fminf(rc, qz - (float)wz0 * GRID_CELL);
        if (wz1 < GRID_G - 1) rc = fminf(rc, (float)(wz1 + 1) * GRID_CELL - qz);
        float rc2 = rc * rc * 0.9999f;

        int nx = wx1 - wx0 + 1, nyc = wy1 - wy0 + 1;
        int ns = nx * nyc;
        if (lane < ns) {
            int scx = wx0 + lane / nyc;
            int scy = wy0 + lane % nyc;
            int b = (scx * GRID_G + scy) * GRID_G;
            int s0 = cellStart[b + wz0];
            int s1 = cellStart[b + wz1 + 1];
            segBase[wave][lane] = s0;
            segPref[wave][lane] = s1 - s0;
        }
        __syncthreads();
        if (lane == 0) {
            int acc = 0;
            for (int s = 0; s < ns; ++s) { int l = segPref[wave][s]; segPref[wave][s] = acc; acc += l; }
            segPref[wave][ns] = acc;
        }
        __syncthreads();

        const int M = segPref[wave][ns];
        bool flag = (M < K_NN) || (M > 320);

        // ---- load up to 5 keys per lane directly from the window
        u64 k0 = ~0ull, k1 = ~0ull, k2 = ~0ull, k3 = ~0ull, k4 = ~0ull;
        {
            int s = 0;
#pragma unroll
            for (int slot = 0; slot < 5; ++slot) {
                int t = lane + slot * 64;
                if (t < M) {
                    while (t >= segPref[wave][s + 1]) ++s;
                    int pos = segBase[wave][s] + (t - segPref[wave][s]);
                    float4 v = sp4[pos];
                    float dot = __fmaf_rn(v.z, qz, __fmaf_rn(v.y, qy, __fmul_rn(v.x, qx)));
                    float d2 = __fsub_rn(__fadd_rn(sqi, v.w), __fmul_rn(2.0f, dot));
                    unsigned u = __float_as_uint(d2);
                    u = (u & 0x80000000u) ? ~u : (u | 0x80000000u);
                    u64 key = (((u64)u) << 32) | (unsigned)sidx[pos];
                    if (slot == 0) k0 = key;
                    else if (slot == 1) k1 = key;
                    else if (slot == 2) k2 = key;
                    else if (slot == 3) k3 = key;
                    else k4 = key;
                }
            }
        }

        // ---- selection: 16 wave-argmin rounds over unique (d2, idx) keys
        u64 lm2 = k0; int li = 0;
        if (k1 < lm2) { lm2 = k1; li = 1; }
        if (k2 < lm2) { lm2 = k2; li = 2; }
        if (k3 < lm2) { lm2 = k3; li = 3; }
        if (k4 < lm2) { lm2 = k4; li = 4; }
        int keep = 0;
        u64 last = ~0ull;
#pragma unroll 1
        for (int r = 0; r < 16; ++r) {
            u64 w = lm2;
#pragma unroll
            for (int off = 1; off < 64; off <<= 1) {
                u64 o = __shfl_xor(w, off);
                w = (o < w) ? o : w;
            }
            if (lane == r) keep = (int)(unsigned)(w & 0xffffffffull);
            last = w;
            if (lm2 == w) {
                if (li == 0) k0 = ~0ull;
                else if (li == 1) k1 = ~0ull;
                else if (li == 2) k2 = ~0ull;
                else if (li == 3) k3 = ~0ull;
                else k4 = ~0ull;
                lm2 = k0; li = 0;
                if (k1 < lm2) { lm2 = k1; li = 1; }
                if (k2 < lm2) { lm2 = k2; li = 2; }
                if (k3 < lm2) { lm2 = k3; li = 3; }
                if (k4 < lm2) { lm2 = k4; li = 4; }
            }
        }

        // ---- coverage check on exact d16
        if (!flag) {
            unsigned ou = (unsigned)(last >> 32);
            unsigned db = (ou & 0x80000000u) ? (ou ^ 0x80000000u) : ~ou;
            float d16 = __uint_as_float(db);
            if (d16 >= rc2) flag = true;
        }
        if (flag && lane == 0) {
            int sl = atomicAdd(gcount, 1);
            glist[sl] = q;
        }
        if (lane < 16) idx_out[q * K_NN + lane] = keep;
    } else {
        // ================= proj: T/PG = feats@{theta,phi,g}+b =================
        int pblk = blockIdx.x - KNN_NBLK;
        const int m0 = (pblk & 127) * 64;
        const int sg = pblk >> 7;           // 0..5
        const int sel = sg % 3;
        const int half = sg / 3;
        const bf16_t* Wt = wt_base + sel * (C_DIM * C_DIM);
        const float* bias = (sel == 0) ? tb : (sel == 1) ? phb : gb;
        const int q = lane >> 4, lm = lane & 15;

        bf16x8 bfr[2][8];
#pragma unroll
        for (int ti = 0; ti < 2; ++ti)
#pragma unroll
            for (int kb = 0; kb < 8; ++kb)
                bfr[ti][kb] = *(const bf16x8*)(Wt + (((half * 8 + wave * 2 + ti) * 8 + kb) << 9) + lm * 32 + q * 8);

        float bv[2];
#pragma unroll
        for (int ti = 0; ti < 2; ++ti) bv[ti] = bias[(half * 8 + wave * 2 + ti) * 16 + lm];

#pragma unroll
        for (int p = 0; p < 4; ++p) {
            const bf16_t* arow = fb + (m0 + p * 16 + lm) * C_DIM + q * 8;
            f32x4 acc[2];
            acc[0] = (f32x4){0.f, 0.f, 0.f, 0.f};
            acc[1] = (f32x4){0.f, 0.f, 0.f, 0.f};
#pragma unroll
            for (int kb = 0; kb < 8; ++kb) {
                bf16x8 a = *(const bf16x8*)(arow + kb * 32);
                acc[0] = __builtin_amdgcn_mfma_f32_16x16x32_bf16(a, bfr[0][kb], acc[0], 0, 0, 0);
                acc[1] = __builtin_amdgcn_mfma_f32_16x16x32_bf16(a, bfr[1][kb], acc[1], 0, 0, 0);
            }

#pragma unroll
            for (int ti = 0; ti < 2; ++ti) {
                int c = (half * 8 + wave * 2 + ti) * 16 + lm;
#pragma unroll
                for (int r = 0; r < 4; ++r) {
                    float v = acc[ti][r] + bv[ti];
                    int off = (m0 + p * 16 + q * 4 + r) * C_DIM + c;
                    if (sel == 0) T[off] = v;
                    else if (sel == 1) PG[2 * off] = (bf16_t)v;
                    else PG[2 * off + 1] = (bf16_t)v;
                }
            }
        }
    }
}

// ---------------------------------------------------------------- KNN brute-force fallback for flagged queries
// Grid-stride over glist (32 blocks; ~40 flagged queries expected).
__global__ __launch_bounds__(256) void knn_fallback_kernel(const float* __restrict__ coords,
                                                           const int* __restrict__ glist,
                                                           const int* __restrict__ gcount,
                                                           int* __restrict__ idx_out) {
    const int count = *gcount;
    const int tid = threadIdx.x;
    const int wave = tid >> 6, lane = tid & 63;
    __shared__ float red16[4][16];
    __shared__ u64 cand[4][256];
    __shared__ int cnt[4];
    __shared__ int qids[4];
    const float INF = __int_as_float(0x7f800000);
    const float* cp = coords + tid * 96;

#pragma unroll 1
    for (int n0 = blockIdx.x * 4; n0 < count; n0 += gridDim.x * 4) {
        if (tid < 4) {
            cnt[tid] = 0;
            int slot = n0 + tid;
            qids[tid] = glist[slot < count ? slot : count - 1];
        }
        __syncthreads();

        float qx[4], qy[4], qz[4], sqi[4];
#pragma unroll
        for (int q = 0; q < 4; ++q) {
            int id = qids[q];
            qx[q] = coords[3 * id + 0];
            qy[q] = coords[3 * id + 1];
            qz[q] = coords[3 * id + 2];
            sqi[q] = __fadd_rn(__fadd_rn(__fmul_rn(qx[q], qx[q]), __fmul_rn(qy[q], qy[q])),
                               __fmul_rn(qz[q], qz[q]));
        }

        float lmin[4] = {INF, INF, INF, INF};
#pragma unroll
        for (int c = 0; c < 4; ++c) {
            float buf[24];
#pragma unroll
            for (int v = 0; v < 6; ++v)
                *(float4*)(buf + v * 4) = *(const float4*)(cp + c * 24 + v * 4);
#pragma unroll
            for (int p = 0; p < 8; ++p) {
                float x = buf[3 * p + 0], y = buf[3 * p + 1], z = buf[3 * p + 2];
                float sqj = __fadd_rn(__fadd_rn(__fmul_rn(x, x), __fmul_rn(y, y)),
                                      __fmul_rn(z, z));
#pragma unroll
                for (int q = 0; q < 4; ++q) {
                    float dot = __fmaf_rn(z, qz[q], __fmaf_rn(y, qy[q], __fmul_rn(x, qx[q])));
                    float d2 = __fsub_rn(__fadd_rn(sqi[q], sqj), __fmul_rn(2.0f, dot));
                    lmin[q] = fminf(lmin[q], d2);
                }
            }
        }

#pragma unroll
        for (int q = 0; q < 4; ++q) {
            float g = lmin[q];
            g = fminf(g, __shfl_xor(g, 1));
            g = fminf(g, __shfl_xor(g, 2));
            g = fminf(g, __shfl_xor(g, 4));
            g = fminf(g, __shfl_xor(g, 8));
            if ((lane & 15) == 0) red16[q][wave * 4 + (lane >> 4)] = g;
        }
        __syncthreads();

        float tau[4];
#pragma unroll
        for (int q = 0; q < 4; ++q) {
            float t = red16[q][0];
#pragma unroll
            for (int i = 1; i < 16; ++i) t = fmaxf(t, red16[q][i]);
            tau[q] = t;
        }

#pragma unroll
        for (int c = 0; c < 4; ++c) {
            float buf[24];
#pragma unroll
            for (int v = 0; v < 6; ++v)
                *(float4*)(buf + v * 4) = *(const float4*)(cp + c * 24 + v * 4);
#pragma unroll
            for (int p = 0; p < 8; ++p) {
                float x = buf[3 * p + 0], y = buf[3 * p + 1], z = buf[3 * p + 2];
                float sqj = __fadd_rn(__fadd_rn(__fmul_rn(x, x), __fmul_rn(y, y)),
                                      __fmul_rn(z, z));
                int j = tid * 32 + c * 8 + p;
#pragma unroll
                for (int q = 0; q < 4; ++q) {
                    float dot = __fmaf_rn(z, qz[q], __fmaf_rn(y, qy[q], __fmul_rn(x, qx[q])));
                    float d2 = __fsub_rn(__fadd_rn(sqi[q], sqj), __fmul_rn(2.0f, dot));
                    if (d2 <= tau[q]) {
                        unsigned u = __float_as_uint(d2);
                        u = (u & 0x80000000u) ? ~u : (u | 0x80000000u);
                        int slot = atomicAdd(&cnt[q], 1);
                        if (slot < 256)
                            cand[q][slot] = (((u64)u) << 32) | (unsigned)j;
                    }
                }
            }
        }
        __syncthreads();

        int m = cnt[wave]; if (m > 256) m = 256;
        u64 k0 = ~0ull, k1 = ~0ull, k2 = ~0ull, k3 = ~0ull;
        if (lane < m) k0 = cand[wave][lane];
        if (lane + 64 < m) k1 = cand[wave][lane + 64];
        if (lane + 128 < m) k2 = cand[wave][lane + 128];
        if (lane + 192 < m) k3 = cand[wave][lane + 192];
        u64 lm2 = k0; int li = 0;
        if (k1 < lm2) { lm2 = k1; li = 1; }
        if (k2 < lm2) { lm2 = k2; li = 2; }
        if (k3 < lm2) { lm2 = k3; li = 3; }
        int keep = 0;
#pragma unroll 1
        for (int r = 0; r < 16; ++r) {
            u64 w = lm2;
#pragma unroll
            for (int off = 1; off < 64; off <<= 1) {
                u64 o = __shfl_xor(w, off);
                w = (o < w) ? o : w;
            }
            if (lane == r) keep = (int)(unsigned)(w & 0xffffffffull);
            if (lm2 == w) {
                if (li == 0) k0 = ~0ull;
                else if (li == 1) k1 = ~0ull;
                else if (li == 2) k2 = ~0ull;
                else k3 = ~0ull;
                lm2 = k0; li = 0;
                if (k1 < lm2) { lm2 = k1; li = 1; }
                if (k2 < lm2) { lm2 = k2; li = 2; }
                if (k3 < lm2) { lm2 = k3; li = 3; }
            }
        }
        if (n0 + wave < count && lane < 16)
            idx_out[qids[wave] * K_NN + lane] = keep;
        __syncthreads();   // cand/cnt reuse safe before next grid-stride iteration
    }
}

// ---------------------------------------------------------------- pe1 + pe2 GEMM + softmax + weighted G-sum
//                                                                  + fused FINAL GEMM (out = y@W_w + W_b + feats)
// 512-thread / 8-wave, __launch_bounds__(512,4). Round-12 loop body (inline
// gathers, zero spills) + fused final GEMM. Proven 51.3us (round 15).
#define HPAD 264
#define P_BLK 16
#define HROWS (P_BLK * 16)
__global__ __launch_bounds__(512, 4) void pe2_fused_kernel(
    const float* __restrict__ coords, const int* __restrict__ idx,
    const float* __restrict__ T, const bf16_t* __restrict__ PG,
    const float* __restrict__ w1, const float* __restrict__ b1, const float* __restrict__ b2,
    const bf16_t* __restrict__ Wt2, const bf16_t* __restrict__ Wt3,
    const float* __restrict__ Wb, const float* __restrict__ feats,
    float* __restrict__ out) {
    __shared__ __align__(16) bf16_t hbuf[2][16 * HPAD];
    __shared__ __align__(16) bf16_t yl[16][HPAD];
    __shared__ float dxyz[HROWS][3];
    __shared__ int idxl[HROWS];
    const int tid = threadIdx.x;
    const int p0 = blockIdx.x * P_BLK;
    const int wave = tid >> 6, lane = tid & 63;
    const int q = lane >> 4, lm = lane & 15;

    // 2 col-tiles per wave; global tile index t = wave*2 + ti (0..15)
    bf16x8 bfr[2][8];
#pragma unroll
    for (int ti = 0; ti < 2; ++ti)
#pragma unroll
        for (int kb = 0; kb < 8; ++kb)
            bfr[ti][kb] = *(const bf16x8*)(Wt2 + (((wave * 2 + ti) * 8 + kb) << 9) + lm * 32 + q * 8);
    float b2c[2];
#pragma unroll
    for (int ti = 0; ti < 2; ++ti) b2c[ti] = b2[(wave * 2 + ti) * 16 + lm];

    if (tid < HROWS) {
        int n = p0 + (tid >> 4);
        int j = idx[n * K_NN + (tid & 15)];
        idxl[tid] = j;
        dxyz[tid][0] = coords[3 * j + 0] - coords[3 * n + 0];
        dxyz[tid][1] = coords[3 * j + 1] - coords[3 * n + 1];
        dxyz[tid][2] = coords[3 * j + 2] - coords[3 * n + 2];
    }
    __syncthreads();

    // pe1: thread handles column hc, rows rh..rh+7 of each 16-row tile
    const int hc = tid & 255;
    const int rh = (tid >> 8) * 8;
    const float wx = w1[hc], wy = w1[C_DIM + hc], wz = w1[2 * C_DIM + hc], bb = b1[hc];

    // prologue: stage h rows for lp=0 into buf 0
#pragma unroll
    for (int r = 0; r < 8; ++r) {
        int row = rh + r;
        float pre = dxyz[row][0] * wx + dxyz[row][1] * wy + dxyz[row][2] * wz + bb;
        hbuf[0][row * HPAD + hc] = (bf16_t)fmaxf(pre, 0.0f);
    }
    __syncthreads();

#pragma unroll 1
    for (int lp = 0; lp < P_BLK; ++lp) {
        const int n = p0 + lp;
        const int cur = lp & 1;

        // ---- issue (phi,g) + T gathers first; h-compute + MFMA hide their latency
        int jr[4];
#pragma unroll
        for (int r = 0; r < 4; ++r) jr[r] = idxl[lp * 16 + q * 4 + r];
        bf16x2 pg[2][4];
        float Tn[2];
#pragma unroll
        for (int ti = 0; ti < 2; ++ti) {
            int c = (wave * 2 + ti) * 16 + lm;
            Tn[ti] = T[n * C_DIM + c];
#pragma unroll
            for (int r = 0; r < 4; ++r)
                pg[ti][r] = *(const bf16x2*)(PG + 2 * (jr[r] * C_DIM + c));
        }

        // ---- stage h for lp+1 into the other buffer (VALU work = gather cover)
        if (lp + 1 < P_BLK) {
            int rb = (lp + 1) * 16;
#pragma unroll
            for (int r = 0; r < 8; ++r) {
                int row = rh + r;
                float pre = dxyz[rb + row][0] * wx + dxyz[rb + row][1] * wy
                          + dxyz[rb + row][2] * wz + bb;
                hbuf[cur ^ 1][row * HPAD + hc] = (bf16_t)fmaxf(pre, 0.0f);
            }
        }

        // ---- pe2 GEMM: stream a per-kb (short live range), 2 MFMAs per kb
        const bf16_t* hrow = &hbuf[cur][lm * HPAD + q * 8];
        f32x4 acc[2];
        acc[0] = (f32x4){0.f, 0.f, 0.f, 0.f};
        acc[1] = (f32x4){0.f, 0.f, 0.f, 0.f};
#pragma unroll
        for (int kb = 0; kb < 8; ++kb) {
            bf16x8 a = *(const bf16x8*)(hrow + kb * 32);
            acc[0] = __builtin_amdgcn_mfma_f32_16x16x32_bf16(a, bfr[0][kb], acc[0], 0, 0, 0);
            acc[1] = __builtin_amdgcn_mfma_f32_16x16x32_bf16(a, bfr[1][kb], acc[1], 0, 0, 0);
        }

#pragma unroll
        for (int ti = 0; ti < 2; ++ti) {
            int c = (wave * 2 + ti) * 16 + lm;
            float df[4];
#pragma unroll
            for (int r = 0; r < 4; ++r) {
                float pe = acc[ti][r] + b2c[ti];
                df[r] = (pe * (Tn[ti] - (float)pg[ti][r][0]) + pe) * 0.0625f;
            }
            float mx = fmaxf(fmaxf(df[0], df[1]), fmaxf(df[2], df[3]));
            mx = fmaxf(mx, __shfl_xor(mx, 16));
            mx = fmaxf(mx, __shfl_xor(mx, 32));
            float e[4], s = 0.f;
#pragma unroll
            for (int r = 0; r < 4; ++r) { e[r] = __expf(df[r] - mx); s += e[r]; }
            s += __shfl_xor(s, 16);
            s += __shfl_xor(s, 32);
            float inv = 1.0f / s;
            float y = 0.f;
#pragma unroll
            for (int r = 0; r < 4; ++r) y += e[r] * inv * (float)pg[ti][r][1];
            y += __shfl_xor(y, 16);
            y += __shfl_xor(y, 32);
            if (q == 0) yl[lp][c] = (bf16_t)y;
        }
        __syncthreads();   // hbuf[cur^1] + yl[lp] writes visible
    }

    // ---- fused final GEMM: out[p0..p0+15] = y @ W_w + W_b + feats
#pragma unroll
    for (int ti = 0; ti < 2; ++ti)
#pragma unroll
        for (int kb = 0; kb < 8; ++kb)
            bfr[ti][kb] = *(const bf16x8*)(Wt3 + (((wave * 2 + ti) * 8 + kb) << 9) + lm * 32 + q * 8);
    float bw[2];
#pragma unroll
    for (int ti = 0; ti < 2; ++ti) bw[ti] = Wb[(wave * 2 + ti) * 16 + lm];

    f32x4 acc2[2];
    acc2[0] = (f32x4){0.f, 0.f, 0.f, 0.f};
    acc2[1] = (f32x4){0.f, 0.f, 0.f, 0.f};
#pragma unroll
    for (int kb = 0; kb < 8; ++kb) {
        bf16x8 a = *(const bf16x8*)(&yl[lm][kb * 32 + q * 8]);
        acc2[0] = __builtin_amdgcn_mfma_f32_16x16x32_bf16(a, bfr[0][kb], acc2[0], 0, 0, 0);
        acc2[1] = __builtin_amdgcn_mfma_f32_16x16x32_bf16(a, bfr[1][kb], acc2[1], 0, 0, 0);
    }

#pragma unroll
    for (int ti = 0; ti < 2; ++ti) {
        int c = (wave * 2 + ti) * 16 + lm;
#pragma unroll
        for (int r = 0; r < 4; ++r) {
            int off = (p0 + q * 4 + r) * C_DIM + c;
            out[off] = acc2[ti][r] + bw[ti] + feats[off];
        }
    }
}

// ---------------------------------------------------------------- launch
extern "C" void kernel_launch(void* const* d_in, const int* in_sizes, int n_in,
                              void* d_out, int out_size, void* d_ws, size_t ws_size,
                              hipStream_t stream) {
    const float* coords = (const float*)d_in[0];
    const float* feats  = (const float*)d_in[1];
    const float* theta_w = (const float*)d_in[2];
    const float* theta_b = (const float*)d_in[3];
    const float* phi_w   = (const float*)d_in[4];
    const float* phi_b   = (const float*)d_in[5];
    const float* g_w     = (const float*)d_in[6];
    const float* g_b     = (const float*)d_in[7];
    const float* pe1_w1  = (const float*)d_in[8];
    const float* pe1_b1  = (const float*)d_in[9];
    const float* pe1_w2  = (const float*)d_in[10];
    const float* pe1_b2  = (const float*)d_in[11];
    const float* W_w     = (const float*)d_in[12];
    const float* W_b     = (const float*)d_in[13];
    float* out = (float*)d_out;

    char* w = (char*)d_ws;
    size_t off = 0;
    int* idx = (int*)(w + off);        off += (size_t)N_PTS * K_NN * 4;       // 512 KB
    bf16_t* fb = (bf16_t*)(w + off);   off += (size_t)N_PTS * C_DIM * 2;      // 4 MB
    bf16_t* wt = (bf16_t*)(w + off);   off += (size_t)5 * C_DIM * C_DIM * 2;  // 640 KB
    float* T = (float*)(w + off);      off += (size_t)N_PTS * C_DIM * 4;      // 8 MB
    bf16_t* PG = (bf16_t*)(w + off);   off += (size_t)N_PTS * C_DIM * 4;      // 8 MB (phi,g interleaved)
    // grid-KNN scratch (sp4 16B-aligned)
    float4* sp4 = (float4*)(w + off);  off += (size_t)N_PTS * 16;
    int* sidxp = (int*)(w + off);      off += (size_t)N_PTS * 4;
    int* cid       = (int*)(w + off);  off += (size_t)N_PTS * 4;
    int* cellCount = (int*)(w + off);  off += (size_t)GRID_NC * 4;
    int* cellStart = (int*)(w + off);  off += (size_t)(GRID_NC + 1) * 4;
    int* cellPtr   = (int*)(w + off);  off += (size_t)GRID_NC * 4;
    int* glist = (int*)(w + off);      off += (size_t)N_PTS * 4;
    int* gcount = (int*)(w + off);     off += 256;
    (void)ws_size; (void)in_sizes; (void)n_in; (void)out_size;

    prep_kernel<<<CAST_NBLK + PREPW_NBLK + 16, 256, 0, stream>>>(
        feats, fb, theta_w, phi_w, g_w, pe1_w2, W_w, wt, cellCount, gcount);

    grid_count_kernel<<<N_PTS / 256, 256, 0, stream>>>(coords, cellCount, cid);
    grid_scan_kernel<<<1, 256, 0, stream>>>(cellCount, cellStart, cellPtr);
    grid_scatter_kernel<<<N_PTS / 256, 256, 0, stream>>>(coords, cid, cellPtr, sp4, sidxp);

    // merged: knn_grid (2048 blocks) + proj (768 blocks) co-dispatched
    knn_proj_kernel<<<KNN_NBLK + PROJ_NBLK, 256, 0, stream>>>(
        coords, cellStart, sp4, sidxp, idx, glist, gcount,
        fb, wt, theta_b, phi_b, g_b, T, PG);

    knn_fallback_kernel<<<32, 256, 0, stream>>>(coords, glist, gcount, idx);

    pe2_fused_kernel<<<N_PTS / P_BLK, 512, 0, stream>>>(coords, idx, T, PG,
                                                        pe1_w1, pe1_b1, pe1_b2,
                                                        wt + 3 * C_DIM * C_DIM,
                                                        wt + 4 * C_DIM * C_DIM,
                                                        W_b, feats, out);
}